// Round 1
// baseline (884.695 us; speedup 1.0000x reference)
//
#include <hip/hip_runtime.h>

typedef unsigned long long u64;

#define NN   512
#define DIMF 64
#define EINX 130
#define E2   260
#define MD   17
#define MH   68
#define NH1  128
#define K0   460
#define K1   358
#define K2   307
#define KT   1125
#define O1   460
#define O2   818

__device__ __forceinline__ float siluf(float x) {
    return __fdividef(x, 1.0f + __expf(-x));
}
__device__ __forceinline__ float sigf(float x) {
    return __fdividef(1.0f, 1.0f + __expf(-x));
}
__device__ __forceinline__ void levelOf(int u, int& l, int& a, int& kl, int& off) {
    if (u < K0)      { l = 0; a = u;      kl = K0; off = 0;  }
    else if (u < O2) { l = 1; a = u - O1; kl = K1; off = O1; }
    else             { l = 2; a = u - O2; kl = K2; off = O2; }
}

// ---- ug row bitmasks: ugw[i*8+w] = bits of (edge[i][:]!=0), 64 cols per word
__global__ void k_ug_build(const float* __restrict__ edge, u64* __restrict__ ugw) {
    int i = blockIdx.x;
    int t = threadIdx.x;  // 64
    const float* row = edge + (size_t)i * NN;
    for (int w = 0; w < 8; w++) {
        int col = w * 64 + t;
        u64 m = __ballot(row[col] != 0.0f);
        if (t == 0) ugw[i * 8 + w] = m;
    }
}

// ---- ug2 = (ug @ ug != 0): row i = OR of rows k where ug[i][k]
__global__ void k_ug2(const u64* __restrict__ ugw, u64* __restrict__ ug2w) {
    int gid = blockIdx.x * blockDim.x + threadIdx.x;  // 4096
    int i = gid >> 3, w = gid & 7;
    u64 rm[8];
#pragma unroll
    for (int q = 0; q < 8; q++) rm[q] = ugw[i * 8 + q];
    u64 acc = 0;
    for (int k = 0; k < NN; k++) {
        if ((rm[k >> 6] >> (k & 63)) & 1ULL) acc |= ugw[k * 8 + w];
    }
    ug2w[i * 8 + w] = acc;
}

// ---- pooling scores: sigmoid(feat @ wp[l] + bp[l])
__global__ void k_scores(const float* __restrict__ feat, const float* __restrict__ wp,
                         const float* __restrict__ bp, float* __restrict__ scores) {
    int gid = blockIdx.x * blockDim.x + threadIdx.x;
    if (gid >= 3 * NN) return;
    int l = gid >> 9, n = gid & 511;
    float s = bp[l];
    const float* f = feat + n * DIMF;
    const float* w = wp + l * DIMF;
    for (int d = 0; d < DIMF; d++) s = fmaf(f[d], w[d], s);
    scores[gid] = sigf(s);
}

// ---- full bitonic sort (desc by score, ties by index asc) per level; emit idx/vals/rev
__global__ void k_sort(const float* __restrict__ scores, float* __restrict__ svals,
                       int* __restrict__ sidx, int* __restrict__ rev) {
    int l = blockIdx.x;
    int t = threadIdx.x;  // 512
    __shared__ float sk[NN];
    __shared__ int si[NN];
    sk[t] = scores[l * NN + t];
    si[t] = t;
    rev[l * NN + t] = -1;
    __syncthreads();
    for (int k = 2; k <= NN; k <<= 1) {
        for (int jj = k >> 1; jj > 0; jj >>= 1) {
            int p = t ^ jj;
            if (p > t) {
                float ka = sk[t], kb = sk[p];
                int ia = si[t], ib = si[p];
                bool before = (ka > kb) || (ka == kb && ia < ib);
                bool sw = ((t & k) == 0) ? (!before) : before;
                if (sw) { sk[t] = kb; sk[p] = ka; si[t] = ib; si[p] = ia; }
            }
            __syncthreads();
        }
    }
    svals[l * NN + t] = sk[t];
    sidx[l * NN + t] = si[t];
    int kcnt = (l == 0) ? K0 : (l == 1) ? K1 : K2;
    if (t < kcnt) rev[l * NN + si[t]] = t;
}

// ---- gather subgraph node features (scaled by score) + coords
__global__ void k_gather(const float* __restrict__ feat, const float* __restrict__ coor,
                         const float* __restrict__ svals, const int* __restrict__ sidx,
                         float* __restrict__ hc, float* __restrict__ c0) {
    int u = blockIdx.x;
    int t = threadIdx.x;  // 64
    int l, a, kl, off; levelOf(u, l, a, kl, off);
    int org = sidx[l * NN + a];
    float val = svals[l * NN + a];
    hc[u * DIMF + t] = feat[org * DIMF + t] * val;
    if (t < 3) c0[u * 4 + t] = coor[org * 3 + t];
}

// ---- A = h @ We1[0:64] + be1 (receiver half), B = h @ We1[64:128] (sender half)
__global__ __launch_bounds__(256) void k_ab(int j, const float* __restrict__ We1,
                                            const float* __restrict__ be1,
                                            const float* __restrict__ hc,
                                            float* __restrict__ Ap, float* __restrict__ Bp) {
    int u = blockIdx.x;
    int t = threadIdx.x;
    __shared__ float sh[DIMF];
    if (t < DIMF) sh[t] = hc[u * DIMF + t];
    __syncthreads();
    const float* W = We1 + j * EINX * E2;
    const float* b1 = be1 + j * E2;
    for (int r = t; r < E2; r += 256) {
        float av = b1[r];
        float bv = 0.0f;
        for (int d = 0; d < DIMF; d++) {
            float h = sh[d];
            av = fmaf(h, W[d * E2 + r], av);
            bv = fmaf(h, W[(DIMF + d) * E2 + r], bv);
        }
        Ap[u * E2 + r] = av;
        Bp[u * E2 + r] = bv;
    }
}

// ---- per-pair edge MLP + m_i sum + coordinate update. Block = receiver node u.
// Each lane handles 2 sender pairs to amortize LDS weight broadcasts.
__global__ __launch_bounds__(256) void k_pair(
    int j,
    const float* __restrict__ We1, const float* __restrict__ We2, const float* __restrict__ be2,
    const float* __restrict__ Wc1, const float* __restrict__ bc1,
    const float* __restrict__ Wc2, const float* __restrict__ bc2,
    const float* __restrict__ Ap, const float* __restrict__ Bp,
    const float* __restrict__ cin, float* __restrict__ cout,
    float* __restrict__ mi, const int* __restrict__ sidx, const u64* __restrict__ ug2w) {
    int u = blockIdx.x, t = threadIdx.x;
    int l, a, kl, off; levelOf(u, l, a, kl, off);

    __shared__ __align__(16) float sA[E2];
    __shared__ __align__(16) float swd[E2];
    __shared__ __align__(16) float swe[E2];
    __shared__ float sW2[E2 * MD];
    __shared__ float sWc1[MD * MH];
    __shared__ float sWc2[MH];
    __shared__ float sbc1[MH];
    __shared__ float sbe2[MD];
    __shared__ u64 srow[8];
    __shared__ float sca[4];
    __shared__ float sred[4][20];

    const float* W1 = We1 + j * EINX * E2;
    for (int r = t; r < E2; r += 256) {
        sA[r]  = Ap[u * E2 + r];
        swd[r] = W1[128 * E2 + r];
        swe[r] = W1[129 * E2 + r];
    }
    const float* W2 = We2 + j * E2 * MD;
    for (int x = t; x < E2 * MD; x += 256) sW2[x] = W2[x];
    const float* C1 = Wc1 + j * MD * MH;
    for (int x = t; x < MD * MH; x += 256) sWc1[x] = C1[x];
    if (t < MH) { sWc2[t] = Wc2[j * MH + t]; sbc1[t] = bc1[j * MH + t]; }
    if (t >= MH && t < MH + MD) sbe2[t - MH] = be2[j * MD + (t - MH)];
    if (t >= 128 && t < 136) { int ia = sidx[l * NN + a]; srow[t - 128] = ug2w[ia * 8 + (t - 128)]; }
    if (t >= 136 && t < 139) sca[t - 136] = cin[u * 4 + (t - 136)];
    float bc2v = bc2[j];
    __syncthreads();

    float macc[MD];
#pragma unroll
    for (int o = 0; o < MD; o++) macc[o] = 0.0f;
    float cx = 0.0f, cy = 0.0f, cz = 0.0f;

    int npair = (kl + 1) >> 1;
    if (t < npair) {
        int b0 = 2 * t, b1 = 2 * t + 1;
        float v1ok = 1.0f;
        if (b1 >= kl) { b1 = b0; v1ok = 0.0f; }
        int ub0 = off + b0, ub1 = off + b1;
        float cax = sca[0], cay = sca[1], caz = sca[2];
        float4 cb0 = ((const float4*)cin)[ub0];
        float4 cb1 = ((const float4*)cin)[ub1];
        float rx0 = cax - cb0.x, ry0 = cay - cb0.y, rz0 = caz - cb0.z;
        float rx1 = cax - cb1.x, ry1 = cay - cb1.y, rz1 = caz - cb1.z;
        float d0 = rx0 * rx0 + ry0 * ry0 + rz0 * rz0;
        float d1 = rx1 * rx1 + ry1 * ry1 + rz1 * rz1;
        int i0 = sidx[l * NN + b0];
        int i1 = sidx[l * NN + b1];
        float e0 = (float)((srow[i0 >> 6] >> (i0 & 63)) & 1ULL);
        float e1 = (float)((srow[i1 >> 6] >> (i1 & 63)) & 1ULL);

        float acc0[MD], acc1[MD];
#pragma unroll
        for (int o = 0; o < MD; o++) { acc0[o] = 0.0f; acc1[o] = 0.0f; }

        const float4* B40 = (const float4*)(Bp + ub0 * E2);
        const float4* B41 = (const float4*)(Bp + ub1 * E2);
        const float4* A4 = (const float4*)sA;
        const float4* D4 = (const float4*)swd;
        const float4* E4 = (const float4*)swe;
        for (int r4 = 0; r4 < E2 / 4; r4++) {
            float4 bv0 = B40[r4];
            float4 bv1 = B41[r4];
            float4 av = A4[r4];
            float4 dv = D4[r4];
            float4 ev = E4[r4];
            float s0[4], s1[4];
            s0[0] = siluf(fmaf(e0, ev.x, fmaf(d0, dv.x, av.x + bv0.x)));
            s0[1] = siluf(fmaf(e0, ev.y, fmaf(d0, dv.y, av.y + bv0.y)));
            s0[2] = siluf(fmaf(e0, ev.z, fmaf(d0, dv.z, av.z + bv0.z)));
            s0[3] = siluf(fmaf(e0, ev.w, fmaf(d0, dv.w, av.w + bv0.w)));
            s1[0] = siluf(fmaf(e1, ev.x, fmaf(d1, dv.x, av.x + bv1.x)));
            s1[1] = siluf(fmaf(e1, ev.y, fmaf(d1, dv.y, av.y + bv1.y)));
            s1[2] = siluf(fmaf(e1, ev.z, fmaf(d1, dv.z, av.z + bv1.z)));
            s1[3] = siluf(fmaf(e1, ev.w, fmaf(d1, dv.w, av.w + bv1.w)));
#pragma unroll
            for (int e = 0; e < 4; e++) {
                const float* wrow = &sW2[(r4 * 4 + e) * MD];
#pragma unroll
                for (int o = 0; o < MD; o++) {
                    float w = wrow[o];
                    acc0[o] = fmaf(s0[e], w, acc0[o]);
                    acc1[o] = fmaf(s1[e], w, acc1[o]);
                }
            }
        }
        float m0[MD], m1[MD];
#pragma unroll
        for (int o = 0; o < MD; o++) {
            m0[o] = siluf(acc0[o] + sbe2[o]);
            m1[o] = siluf(acc1[o] + sbe2[o]);
            macc[o] = m0[o] + v1ok * m1[o];
        }
        float cw0 = bc2v, cw1 = bc2v;
        for (int hh = 0; hh < MH; hh++) {
            float p0 = sbc1[hh], p1 = sbc1[hh];
#pragma unroll
            for (int o = 0; o < MD; o++) {
                float w = sWc1[o * MH + hh];
                p0 = fmaf(m0[o], w, p0);
                p1 = fmaf(m1[o], w, p1);
            }
            float wc2 = sWc2[hh];
            cw0 = fmaf(siluf(p0), wc2, cw0);
            cw1 = fmaf(siluf(p1), wc2, cw1);
        }
        cw1 *= v1ok;
        cx = fmaf(cw0, rx0, cw1 * rx1);
        cy = fmaf(cw0, ry0, cw1 * ry1);
        cz = fmaf(cw0, rz0, cw1 * rz1);
    }

#pragma unroll
    for (int o = 0; o < MD; o++) {
        float v = macc[o];
        for (int s = 32; s > 0; s >>= 1) v += __shfl_down(v, s);
        macc[o] = v;
    }
    for (int s = 32; s > 0; s >>= 1) cx += __shfl_down(cx, s);
    for (int s = 32; s > 0; s >>= 1) cy += __shfl_down(cy, s);
    for (int s = 32; s > 0; s >>= 1) cz += __shfl_down(cz, s);
    int wv = t >> 6, ln = t & 63;
    if (ln == 0) {
#pragma unroll
        for (int o = 0; o < MD; o++) sred[wv][o] = macc[o];
        sred[wv][17] = cx; sred[wv][18] = cy; sred[wv][19] = cz;
    }
    __syncthreads();
    if (t < 20) {
        float s = sred[0][t] + sred[1][t] + sred[2][t] + sred[3][t];
        if (t < MD) mi[u * 20 + t] = s;
        else cout[u * 4 + (t - MD)] = sca[t - MD] + s;
    }
}

// ---- node MLP: hc = relu(2*hc + (silu([hc,m_i]@Wn1+bn1)@Wn2 + bn2))
__global__ __launch_bounds__(128) void k_node(
    int j, const float* __restrict__ Wn1, const float* __restrict__ bn1,
    const float* __restrict__ Wn2, const float* __restrict__ bn2,
    float* __restrict__ hc, const float* __restrict__ mi) {
    int u = blockIdx.x, t = threadIdx.x;
    __shared__ float sin_[DIMF + MD];
    __shared__ float st[NH1];
    if (t < DIMF) sin_[t] = hc[u * DIMF + t];
    else if (t < DIMF + MD) sin_[t] = mi[u * 20 + (t - DIMF)];
    __syncthreads();
    const float* W1 = Wn1 + j * (DIMF + MD) * NH1;
    float v = bn1[j * NH1 + t];
    for (int i = 0; i < DIMF + MD; i++) v = fmaf(sin_[i], W1[i * NH1 + t], v);
    st[t] = siluf(v);
    __syncthreads();
    if (t < DIMF) {
        const float* W2 = Wn2 + j * NH1 * DIMF;
        float h = bn2[j * DIMF + t];
        for (int i = 0; i < NH1; i++) h = fmaf(st[i], W2[i * DIMF + t], h);
        float hv = sin_[t];
        hc[u * DIMF + t] = fmaxf(0.0f, fmaf(2.0f, hv, h));
    }
}

// ---- scatter back through rev-index maps + elementwise max over 3 levels
__global__ void k_final(const float* __restrict__ hc, const int* __restrict__ rev,
                        float* __restrict__ out) {
    int gid = blockIdx.x * blockDim.x + threadIdx.x;
    if (gid >= NN * DIMF) return;
    int n = gid >> 6, d = gid & 63;
    float v = 0.0f;
    int a0 = rev[0 * NN + n];
    if (a0 >= 0) v = fmaxf(v, hc[(0 + a0) * DIMF + d]);
    int a1 = rev[1 * NN + n];
    if (a1 >= 0) v = fmaxf(v, hc[(O1 + a1) * DIMF + d]);
    int a2 = rev[2 * NN + n];
    if (a2 >= 0) v = fmaxf(v, hc[(O2 + a2) * DIMF + d]);
    out[gid] = v;
}

extern "C" void kernel_launch(void* const* d_in, const int* in_sizes, int n_in,
                              void* d_out, int out_size, void* d_ws, size_t ws_size,
                              hipStream_t stream) {
    (void)in_sizes; (void)n_in; (void)out_size; (void)ws_size;
    const float* feat = (const float*)d_in[0];
    const float* coor = (const float*)d_in[1];
    const float* edge = (const float*)d_in[2];
    const float* We1  = (const float*)d_in[3];
    const float* be1  = (const float*)d_in[4];
    const float* We2  = (const float*)d_in[5];
    const float* be2  = (const float*)d_in[6];
    const float* Wc1  = (const float*)d_in[7];
    const float* bc1  = (const float*)d_in[8];
    const float* Wc2  = (const float*)d_in[9];
    const float* bc2  = (const float*)d_in[10];
    const float* Wn1  = (const float*)d_in[11];
    const float* bn1  = (const float*)d_in[12];
    const float* Wn2  = (const float*)d_in[13];
    const float* bn2  = (const float*)d_in[14];
    const float* wp   = (const float*)d_in[15];
    const float* bp   = (const float*)d_in[16];
    float* out = (float*)d_out;

    char* wsb = (char*)d_ws;
    u64*   ugw    = (u64*)(wsb + 0);        // 32768 B
    u64*   ug2w   = (u64*)(wsb + 32768);    // 32768 B
    float* scores = (float*)(wsb + 65536);  // 6144 B
    float* svals  = (float*)(wsb + 71680);  // 6144 B
    int*   sidx   = (int*)(wsb + 77824);    // 6144 B
    int*   rev    = (int*)(wsb + 83968);    // 6144 B
    float* c0     = (float*)(wsb + 90112);  // 18176 B
    float* c1     = (float*)(wsb + 108288); // 18176 B
    float* mi     = (float*)(wsb + 126464); // 90112 B
    float* hc     = (float*)(wsb + 216576); // 288256 B
    float* Ap     = (float*)(wsb + 504832); // 1170176 B
    float* Bp     = (float*)(wsb + 1675008);// 1170176 B  (end ~2.85 MB)

    k_ug_build<<<NN, 64, 0, stream>>>(edge, ugw);
    k_ug2<<<16, 256, 0, stream>>>(ugw, ug2w);
    k_scores<<<6, 256, 0, stream>>>(feat, wp, bp, scores);
    k_sort<<<3, NN, 0, stream>>>(scores, svals, sidx, rev);
    k_gather<<<KT, 64, 0, stream>>>(feat, coor, svals, sidx, hc, c0);
    k_ab<<<KT, 256, 0, stream>>>(0, We1, be1, hc, Ap, Bp);
    for (int j = 0; j < 3; j++) {
        const float* ci = (j & 1) ? c1 : c0;
        float* co = (j & 1) ? c0 : c1;
        k_pair<<<KT, 256, 0, stream>>>(j, We1, We2, be2, Wc1, bc1, Wc2, bc2,
                                       Ap, Bp, ci, co, mi, sidx, ug2w);
        k_node<<<KT, 128, 0, stream>>>(j, Wn1, bn1, Wn2, bn2, hc, mi);
        if (j < 2) k_ab<<<KT, 256, 0, stream>>>(j + 1, We1, be1, hc, Ap, Bp);
    }
    k_final<<<(NN * DIMF) / 256, 256, 0, stream>>>(hc, rev, out);
}

// Round 2
// 850.907 us; speedup vs baseline: 1.0397x; 1.0397x over previous
//
#include <hip/hip_runtime.h>

typedef unsigned long long u64;

#define NN   512
#define DIMF 64
#define EINX 130
#define E2   260
#define MD   17
#define MH   68
#define NH1  128
#define K0   460
#define K1   358
#define K2   307
#define KT   1125
#define O1   460
#define O2   818
#define PADU 1128   // padded node stride for BpT
#define WPAD 20     // padded row stride for W2P / Wc1T

union F4 { float4 v; float f[4]; };

__device__ __forceinline__ float siluf(float x) {
    return __fdividef(x, 1.0f + __expf(-x));
}
__device__ __forceinline__ float sigf(float x) {
    return __fdividef(1.0f, 1.0f + __expf(-x));
}
__device__ __forceinline__ void levelOf(int u, int& l, int& a, int& kl, int& off) {
    if (u < K0)      { l = 0; a = u;      kl = K0; off = 0;  }
    else if (u < O2) { l = 1; a = u - O1; kl = K1; off = O1; }
    else             { l = 2; a = u - O2; kl = K2; off = O2; }
}

// ---- ug row bitmasks
__global__ void k_ug_build(const float* __restrict__ edge, u64* __restrict__ ugw) {
    int i = blockIdx.x;
    int t = threadIdx.x;  // 64
    const float* row = edge + (size_t)i * NN;
    for (int w = 0; w < 8; w++) {
        int col = w * 64 + t;
        u64 m = __ballot(row[col] != 0.0f);
        if (t == 0) ugw[i * 8 + w] = m;
    }
}

// ---- ug2 = (ug @ ug != 0)
__global__ void k_ug2(const u64* __restrict__ ugw, u64* __restrict__ ug2w) {
    int gid = blockIdx.x * blockDim.x + threadIdx.x;  // 4096
    int i = gid >> 3, w = gid & 7;
    u64 rm[8];
#pragma unroll
    for (int q = 0; q < 8; q++) rm[q] = ugw[i * 8 + q];
    u64 acc = 0;
    for (int k = 0; k < NN; k++) {
        if ((rm[k >> 6] >> (k & 63)) & 1ULL) acc |= ugw[k * 8 + w];
    }
    ug2w[i * 8 + w] = acc;
}

// ---- pooling scores
__global__ void k_scores(const float* __restrict__ feat, const float* __restrict__ wp,
                         const float* __restrict__ bp, float* __restrict__ scores) {
    int gid = blockIdx.x * blockDim.x + threadIdx.x;
    if (gid >= 3 * NN) return;
    int l = gid >> 9, n = gid & 511;
    float s = bp[l];
    const float* f = feat + n * DIMF;
    const float* w = wp + l * DIMF;
    for (int d = 0; d < DIMF; d++) s = fmaf(f[d], w[d], s);
    scores[gid] = sigf(s);
}

// ---- bitonic sort per level
__global__ void k_sort(const float* __restrict__ scores, float* __restrict__ svals,
                       int* __restrict__ sidx, int* __restrict__ rev) {
    int l = blockIdx.x;
    int t = threadIdx.x;  // 512
    __shared__ float sk[NN];
    __shared__ int si[NN];
    sk[t] = scores[l * NN + t];
    si[t] = t;
    rev[l * NN + t] = -1;
    __syncthreads();
    for (int k = 2; k <= NN; k <<= 1) {
        for (int jj = k >> 1; jj > 0; jj >>= 1) {
            int p = t ^ jj;
            if (p > t) {
                float ka = sk[t], kb = sk[p];
                int ia = si[t], ib = si[p];
                bool before = (ka > kb) || (ka == kb && ia < ib);
                bool sw = ((t & k) == 0) ? (!before) : before;
                if (sw) { sk[t] = kb; sk[p] = ka; si[t] = ib; si[p] = ia; }
            }
            __syncthreads();
        }
    }
    svals[l * NN + t] = sk[t];
    sidx[l * NN + t] = si[t];
    int kcnt = (l == 0) ? K0 : (l == 1) ? K1 : K2;
    if (t < kcnt) rev[l * NN + si[t]] = t;
}

// ---- gather subgraph features + coords
__global__ void k_gather(const float* __restrict__ feat, const float* __restrict__ coor,
                         const float* __restrict__ svals, const int* __restrict__ sidx,
                         float* __restrict__ hc, float* __restrict__ c0) {
    int u = blockIdx.x;
    int t = threadIdx.x;  // 64
    int l, a, kl, off; levelOf(u, l, a, kl, off);
    int org = sidx[l * NN + a];
    float val = svals[l * NN + a];
    hc[u * DIMF + t] = feat[org * DIMF + t] * val;
    if (t < 3) c0[u * 4 + t] = coor[org * 3 + t];
}

// ---- weight prep: pad We2 rows to 20, transpose+pad Wc1 to [hh][o] rows of 20
__global__ void k_prep(const float* __restrict__ We2, const float* __restrict__ Wc1,
                       float* __restrict__ W2P, float* __restrict__ Wc1T) {
    int tid = blockIdx.x * blockDim.x + threadIdx.x;
    int stride = gridDim.x * blockDim.x;
    for (int x = tid; x < 3 * E2 * WPAD; x += stride) {
        int jj = x / (E2 * WPAD), r = x % (E2 * WPAD);
        int k = r / WPAD, o = r % WPAD;
        W2P[x] = (o < MD) ? We2[jj * E2 * MD + k * MD + o] : 0.0f;
    }
    for (int x = tid; x < 3 * MH * WPAD; x += stride) {
        int jj = x / (MH * WPAD), r = x % (MH * WPAD);
        int hh = r / WPAD, o = r % WPAD;
        Wc1T[x] = (o < MD) ? Wc1[jj * MD * MH + o * MH + hh] : 0.0f;
    }
}

// ---- A = h @ We1[0:64] + be1 (row-major per node); B^T = (h @ We1[64:128])^T
__global__ __launch_bounds__(256) void k_ab(int j, const float* __restrict__ We1,
                                            const float* __restrict__ be1,
                                            const float* __restrict__ hcg,
                                            float* __restrict__ Ap, float* __restrict__ BpT) {
    int u = blockIdx.x;
    int t = threadIdx.x;
    const float* W = We1 + j * EINX * E2;
    const float* h = hcg + u * DIMF;   // uniform reads -> scalar path
    for (int r = t; r < E2; r += 256) {
        float av = be1[j * E2 + r];
        float bv = 0.0f;
        for (int d = 0; d < DIMF; d++) {
            float hv = h[d];
            av = fmaf(hv, W[d * E2 + r], av);
            bv = fmaf(hv, W[(DIMF + d) * E2 + r], bv);
        }
        Ap[u * E2 + r] = av;
        BpT[r * PADU + u] = bv;
    }
}

// ---- per-pair edge MLP + m_i sum + coord update. Block = receiver u, 128 thr,
// 4 pair-slots per lane (stride 128). Weights read via wave-uniform global
// loads (scalar path), B via lane-coalesced transposed loads. No bulk LDS.
__global__ __launch_bounds__(128) void k_pair(
    int j,
    const float* __restrict__ We1,   // wd/we rows
    const float* __restrict__ W2P,   // [3][260][20]
    const float* __restrict__ be2,
    const float* __restrict__ Wc1T,  // [3][68][20]
    const float* __restrict__ bc1,
    const float* __restrict__ Wc2,
    const float* __restrict__ bc2,
    const float* __restrict__ Ap,
    const float* __restrict__ BpT,   // [260][PADU]
    const float* __restrict__ cin, float* __restrict__ cout,
    float* __restrict__ mi, const int* __restrict__ sidx,
    const u64* __restrict__ ug2w) {
    int u = blockIdx.x, t = threadIdx.x;
    int l, a, kl, off; levelOf(u, l, a, kl, off);

    __shared__ u64 srow[8];
    __shared__ float sca[4];
    __shared__ float sred[2][20];

    if (t < 8) { int ia = sidx[l * NN + a]; srow[t] = ug2w[ia * 8 + t]; }
    if (t >= 8 && t < 12) sca[t - 8] = cin[u * 4 + (t - 8)];
    __syncthreads();

    float cax = sca[0], cay = sca[1], caz = sca[2];
    float act[4], d_[4], ef[4], rx[4], ry[4], rz[4];
    int ub[4];
#pragma unroll
    for (int p = 0; p < 4; p++) {
        int b = t + p * 128;
        act[p] = (b < kl) ? 1.0f : 0.0f;
        if (b >= kl) b = 0;
        ub[p] = off + b;
        F4 cb; cb.v = ((const float4*)cin)[ub[p]];
        rx[p] = cax - cb.f[0]; ry[p] = cay - cb.f[1]; rz[p] = caz - cb.f[2];
        d_[p] = rx[p] * rx[p] + ry[p] * ry[p] + rz[p] * rz[p];
        int ib = sidx[l * NN + b];
        ef[p] = (float)((srow[ib >> 6] >> (ib & 63)) & 1ULL);
    }

    const float* A  = Ap + u * E2;
    const float* WD = We1 + j * EINX * E2 + 128 * E2;
    const float* WE = WD + E2;
    const float* W2 = W2P + j * E2 * WPAD;

    float acc[4][MD];
#pragma unroll
    for (int p = 0; p < 4; p++)
#pragma unroll
        for (int o = 0; o < MD; o++) acc[p][o] = 0.0f;

    for (int r4 = 0; r4 < E2 / 4; r4++) {
        F4 a4, wd4, we4;
        a4.v  = *(const float4*)(A  + 4 * r4);
        wd4.v = *(const float4*)(WD + 4 * r4);
        we4.v = *(const float4*)(WE + 4 * r4);
        float s[4][4];
#pragma unroll
        for (int e = 0; e < 4; e++) {
            int k = 4 * r4 + e;
            const float* bt = BpT + k * PADU;
            float base = a4.f[e], wde = wd4.f[e], wee = we4.f[e];
#pragma unroll
            for (int p = 0; p < 4; p++) {
                float bv = bt[ub[p]];
                s[p][e] = siluf(fmaf(d_[p], wde, fmaf(ef[p], wee, base + bv)));
            }
        }
        const float* wr = W2 + r4 * 4 * WPAD;
#pragma unroll
        for (int e = 0; e < 4; e++) {
#pragma unroll
            for (int o = 0; o < MD; o++) {
                float w = wr[e * WPAD + o];
#pragma unroll
                for (int p = 0; p < 4; p++)
                    acc[p][o] = fmaf(s[p][e], w, acc[p][o]);
            }
        }
    }

    // m = silu(acc + be2); masked sum for m_i
    float macc[MD];
#pragma unroll
    for (int o = 0; o < MD; o++) {
        float be = be2[j * MD + o];
        float s0 = 0.0f;
#pragma unroll
        for (int p = 0; p < 4; p++) {
            acc[p][o] = siluf(acc[p][o] + be);
            s0 = fmaf(act[p], acc[p][o], s0);
        }
        macc[o] = s0;
    }

    // coord MLP: cw = silu(m@Wc1+bc1)@Wc2+bc2
    float bc2v = bc2[j];
    float cw[4] = {bc2v, bc2v, bc2v, bc2v};
    const float* C1 = Wc1T + j * MH * WPAD;
    const float* C2 = Wc2 + j * MH;
    const float* B1 = bc1 + j * MH;
    for (int hh = 0; hh < MH; hh++) {
        const float* wr = C1 + hh * WPAD;
        float bb = B1[hh], w2 = C2[hh];
        float pre[4] = {bb, bb, bb, bb};
#pragma unroll
        for (int o = 0; o < MD; o++) {
            float w = wr[o];
#pragma unroll
            for (int p = 0; p < 4; p++) pre[p] = fmaf(acc[p][o], w, pre[p]);
        }
#pragma unroll
        for (int p = 0; p < 4; p++) cw[p] = fmaf(siluf(pre[p]), w2, cw[p]);
    }
    float cx = 0.0f, cy = 0.0f, cz = 0.0f;
#pragma unroll
    for (int p = 0; p < 4; p++) {
        float c = cw[p] * act[p];
        cx = fmaf(c, rx[p], cx);
        cy = fmaf(c, ry[p], cy);
        cz = fmaf(c, rz[p], cz);
    }

    // reduce 17 m_i values + 3 coord deltas across 128 threads
#pragma unroll
    for (int o = 0; o < MD; o++) {
        float v = macc[o];
        for (int s = 32; s > 0; s >>= 1) v += __shfl_down(v, s);
        macc[o] = v;
    }
    for (int s = 32; s > 0; s >>= 1) cx += __shfl_down(cx, s);
    for (int s = 32; s > 0; s >>= 1) cy += __shfl_down(cy, s);
    for (int s = 32; s > 0; s >>= 1) cz += __shfl_down(cz, s);
    int wv = t >> 6, ln = t & 63;
    if (ln == 0) {
#pragma unroll
        for (int o = 0; o < MD; o++) sred[wv][o] = macc[o];
        sred[wv][17] = cx; sred[wv][18] = cy; sred[wv][19] = cz;
    }
    __syncthreads();
    if (t < 20) {
        float s = sred[0][t] + sred[1][t];
        if (t < MD) mi[u * 20 + t] = s;
        else cout[u * 4 + (t - MD)] = sca[t - MD] + s;
    }
}

// ---- node MLP: hc = relu(2*hc + (silu([hc,m_i]@Wn1+bn1)@Wn2 + bn2))
__global__ __launch_bounds__(128) void k_node(
    int j, const float* __restrict__ Wn1, const float* __restrict__ bn1,
    const float* __restrict__ Wn2, const float* __restrict__ bn2,
    float* __restrict__ hc, const float* __restrict__ mi) {
    int u = blockIdx.x, t = threadIdx.x;
    __shared__ float sin_[DIMF + MD];
    __shared__ float st[NH1];
    if (t < DIMF) sin_[t] = hc[u * DIMF + t];
    else if (t < DIMF + MD) sin_[t] = mi[u * 20 + (t - DIMF)];
    __syncthreads();
    const float* W1 = Wn1 + j * (DIMF + MD) * NH1;
    float v = bn1[j * NH1 + t];
    for (int i = 0; i < DIMF + MD; i++) v = fmaf(sin_[i], W1[i * NH1 + t], v);
    st[t] = siluf(v);
    __syncthreads();
    if (t < DIMF) {
        const float* W2 = Wn2 + j * NH1 * DIMF;
        float h = bn2[j * DIMF + t];
        for (int i = 0; i < NH1; i++) h = fmaf(st[i], W2[i * DIMF + t], h);
        float hv = sin_[t];
        hc[u * DIMF + t] = fmaxf(0.0f, fmaf(2.0f, hv, h));
    }
}

// ---- scatter + 3-level max
__global__ void k_final(const float* __restrict__ hc, const int* __restrict__ rev,
                        float* __restrict__ out) {
    int gid = blockIdx.x * blockDim.x + threadIdx.x;
    if (gid >= NN * DIMF) return;
    int n = gid >> 6, d = gid & 63;
    float v = 0.0f;
    int a0 = rev[0 * NN + n];
    if (a0 >= 0) v = fmaxf(v, hc[(0 + a0) * DIMF + d]);
    int a1 = rev[1 * NN + n];
    if (a1 >= 0) v = fmaxf(v, hc[(O1 + a1) * DIMF + d]);
    int a2 = rev[2 * NN + n];
    if (a2 >= 0) v = fmaxf(v, hc[(O2 + a2) * DIMF + d]);
    out[gid] = v;
}

extern "C" void kernel_launch(void* const* d_in, const int* in_sizes, int n_in,
                              void* d_out, int out_size, void* d_ws, size_t ws_size,
                              hipStream_t stream) {
    (void)in_sizes; (void)n_in; (void)out_size; (void)ws_size;
    const float* feat = (const float*)d_in[0];
    const float* coor = (const float*)d_in[1];
    const float* edge = (const float*)d_in[2];
    const float* We1  = (const float*)d_in[3];
    const float* be1  = (const float*)d_in[4];
    const float* We2  = (const float*)d_in[5];
    const float* be2  = (const float*)d_in[6];
    const float* Wc1  = (const float*)d_in[7];
    const float* bc1  = (const float*)d_in[8];
    const float* Wc2  = (const float*)d_in[9];
    const float* bc2  = (const float*)d_in[10];
    const float* Wn1  = (const float*)d_in[11];
    const float* bn1  = (const float*)d_in[12];
    const float* Wn2  = (const float*)d_in[13];
    const float* bn2  = (const float*)d_in[14];
    const float* wp   = (const float*)d_in[15];
    const float* bp   = (const float*)d_in[16];
    float* out = (float*)d_out;

    char* wsb = (char*)d_ws;
    u64*   ugw    = (u64*)(wsb + 0);        // 32768
    u64*   ug2w   = (u64*)(wsb + 32768);    // 32768
    float* scores = (float*)(wsb + 65536);  // 6144
    float* svals  = (float*)(wsb + 71680);  // 6144
    int*   sidx   = (int*)(wsb + 77824);    // 6144
    int*   rev    = (int*)(wsb + 83968);    // 6144
    float* c0     = (float*)(wsb + 90112);  // 18176
    float* c1     = (float*)(wsb + 108288); // 18176
    float* mi     = (float*)(wsb + 126464); // 90112
    float* hc     = (float*)(wsb + 216576); // 288256
    float* Ap     = (float*)(wsb + 504832); // 1170176
    float* BpT    = (float*)(wsb + 1675008);// 1173504 (260*1128*4)
    float* W2P    = (float*)(wsb + 2848512);// 62464   (3*260*20*4)
    float* Wc1T   = (float*)(wsb + 2910976);// 16320   (3*68*20*4)  end ~2.93 MB

    k_prep<<<8, 256, 0, stream>>>(We2, Wc1, W2P, Wc1T);
    k_ug_build<<<NN, 64, 0, stream>>>(edge, ugw);
    k_ug2<<<16, 256, 0, stream>>>(ugw, ug2w);
    k_scores<<<6, 256, 0, stream>>>(feat, wp, bp, scores);
    k_sort<<<3, NN, 0, stream>>>(scores, svals, sidx, rev);
    k_gather<<<KT, 64, 0, stream>>>(feat, coor, svals, sidx, hc, c0);
    k_ab<<<KT, 256, 0, stream>>>(0, We1, be1, hc, Ap, BpT);
    for (int j = 0; j < 3; j++) {
        const float* ci = (j & 1) ? c1 : c0;
        float* co = (j & 1) ? c0 : c1;
        k_pair<<<KT, 128, 0, stream>>>(j, We1, W2P, be2, Wc1T, bc1, Wc2, bc2,
                                       Ap, BpT, ci, co, mi, sidx, ug2w);
        k_node<<<KT, 128, 0, stream>>>(j, Wn1, bn1, Wn2, bn2, hc, mi);
        if (j < 2) k_ab<<<KT, 256, 0, stream>>>(j + 1, We1, be1, hc, Ap, BpT);
    }
    k_final<<<(NN * DIMF) / 256, 256, 0, stream>>>(hc, rev, out);
}

// Round 3
// 695.970 us; speedup vs baseline: 1.2712x; 1.2226x over previous
//
#include <hip/hip_runtime.h>

typedef unsigned long long u64;

#define NN   512
#define DIMF 64
#define EINX 130
#define E2   260
#define MD   17
#define MH   68
#define NH1  128
#define K0   460
#define K1   358
#define K2   307
#define KT   1125
#define O1   460
#define O2   818
#define PADU 1128   // padded node stride for BpT
#define WPAD 20     // padded row stride for W2P / Wc1T

// sender-tile task decomposition: tiles of 64 senders per wave
#define NT0  8      // ceil(460/64)
#define NT1  6      // ceil(358/64)
#define NT2  5      // ceil(307/64)
#define T0TASK  (K0 * NT0)            // 3680
#define T01TASK (T0TASK + K1 * NT1)   // 5828
#define TTOT    (T01TASK + K2 * NT2)  // 7363
#define PAIRBLOCKS ((TTOT + 3) / 4)   // 1841 blocks of 4 waves

union F4 { float4 v; float f[4]; };

__device__ __forceinline__ float siluf(float x) {
    return __fdividef(x, 1.0f + __expf(-x));
}
__device__ __forceinline__ float sigf(float x) {
    return __fdividef(1.0f, 1.0f + __expf(-x));
}

// ---- ug row bitmasks
__global__ void k_ug_build(const float* __restrict__ edge, u64* __restrict__ ugw) {
    int i = blockIdx.x;
    int t = threadIdx.x;  // 64
    const float* row = edge + (size_t)i * NN;
    for (int w = 0; w < 8; w++) {
        int col = w * 64 + t;
        u64 m = __ballot(row[col] != 0.0f);
        if (t == 0) ugw[i * 8 + w] = m;
    }
}

// ---- ug2 = (ug @ ug != 0)
__global__ void k_ug2(const u64* __restrict__ ugw, u64* __restrict__ ug2w) {
    int gid = blockIdx.x * blockDim.x + threadIdx.x;  // 4096
    int i = gid >> 3, w = gid & 7;
    u64 rm[8];
#pragma unroll
    for (int q = 0; q < 8; q++) rm[q] = ugw[i * 8 + q];
    u64 acc = 0;
    for (int k = 0; k < NN; k++) {
        if ((rm[k >> 6] >> (k & 63)) & 1ULL) acc |= ugw[k * 8 + w];
    }
    ug2w[i * 8 + w] = acc;
}

// ---- pooling scores
__global__ void k_scores(const float* __restrict__ feat, const float* __restrict__ wp,
                         const float* __restrict__ bp, float* __restrict__ scores) {
    int gid = blockIdx.x * blockDim.x + threadIdx.x;
    if (gid >= 3 * NN) return;
    int l = gid >> 9, n = gid & 511;
    float s = bp[l];
    const float* f = feat + n * DIMF;
    const float* w = wp + l * DIMF;
    for (int d = 0; d < DIMF; d++) s = fmaf(f[d], w[d], s);
    scores[gid] = sigf(s);
}

// ---- bitonic sort per level
__global__ void k_sort(const float* __restrict__ scores, float* __restrict__ svals,
                       int* __restrict__ sidx, int* __restrict__ rev) {
    int l = blockIdx.x;
    int t = threadIdx.x;  // 512
    __shared__ float sk[NN];
    __shared__ int si[NN];
    sk[t] = scores[l * NN + t];
    si[t] = t;
    rev[l * NN + t] = -1;
    __syncthreads();
    for (int k = 2; k <= NN; k <<= 1) {
        for (int jj = k >> 1; jj > 0; jj >>= 1) {
            int p = t ^ jj;
            if (p > t) {
                float ka = sk[t], kb = sk[p];
                int ia = si[t], ib = si[p];
                bool before = (ka > kb) || (ka == kb && ia < ib);
                bool sw = ((t & k) == 0) ? (!before) : before;
                if (sw) { sk[t] = kb; sk[p] = ka; si[t] = ib; si[p] = ia; }
            }
            __syncthreads();
        }
    }
    svals[l * NN + t] = sk[t];
    sidx[l * NN + t] = si[t];
    int kcnt = (l == 0) ? K0 : (l == 1) ? K1 : K2;
    if (t < kcnt) rev[l * NN + si[t]] = t;
}

// ---- gather subgraph features + coords
__global__ void k_gather(const float* __restrict__ feat, const float* __restrict__ coor,
                         const float* __restrict__ svals, const int* __restrict__ sidx,
                         float* __restrict__ hc, float* __restrict__ c0) {
    int u = blockIdx.x;
    int t = threadIdx.x;  // 64
    int l = (u < K0) ? 0 : (u < O2) ? 1 : 2;
    int a = u - ((l == 0) ? 0 : (l == 1) ? O1 : O2);
    int org = sidx[l * NN + a];
    float val = svals[l * NN + a];
    hc[u * DIMF + t] = feat[org * DIMF + t] * val;
    if (t < 3) c0[u * 4 + t] = coor[org * 3 + t];
}

// ---- weight prep: pad We2 rows to 20, transpose+pad Wc1 to [hh][o] rows of 20
__global__ void k_prep(const float* __restrict__ We2, const float* __restrict__ Wc1,
                       float* __restrict__ W2P, float* __restrict__ Wc1T) {
    int tid = blockIdx.x * blockDim.x + threadIdx.x;
    int stride = gridDim.x * blockDim.x;
    for (int x = tid; x < 3 * E2 * WPAD; x += stride) {
        int jj = x / (E2 * WPAD), r = x % (E2 * WPAD);
        int k = r / WPAD, o = r % WPAD;
        W2P[x] = (o < MD) ? We2[jj * E2 * MD + k * MD + o] : 0.0f;
    }
    for (int x = tid; x < 3 * MH * WPAD; x += stride) {
        int jj = x / (MH * WPAD), r = x % (MH * WPAD);
        int hh = r / WPAD, o = r % WPAD;
        Wc1T[x] = (o < MD) ? Wc1[jj * MD * MH + o * MH + hh] : 0.0f;
    }
}

// ---- A = h @ We1[0:64] + be1; B^T = (h @ We1[64:128])^T.
// 4 nodes per block (one per wave); lane owns 4 consecutive r (float4),
// lanes 0-3 additionally own the tail r=256..259 fused into the same d-loop.
// Also zero-inits mi and copies cin->cout for the following k_pair's atomics.
__global__ __launch_bounds__(256) void k_ab(int j, const float* __restrict__ We1,
                                            const float* __restrict__ be1,
                                            const float* __restrict__ hcg,
                                            float* __restrict__ Ap, float* __restrict__ BpT,
                                            const float* __restrict__ ci, float* __restrict__ co,
                                            float* __restrict__ mi) {
    int t = threadIdx.x;
    int u = blockIdx.x * 4 + (t >> 6);
    if (u >= KT) return;
    int lane = t & 63;
    if (lane < 20) mi[u * 20 + lane] = 0.0f;
    else if (lane < 24) co[u * 4 + (lane - 20)] = ci[u * 4 + (lane - 20)];

    const float* W = We1 + j * EINX * E2;
    const float* h = hcg + u * DIMF;
    int r = 4 * lane;                 // 0..252
    int rt = 256 + lane;              // tail element, valid for lane<4
    int rtc = (rt < E2) ? rt : 0;     // clamped for be1 read safety
    F4 av; av.v = *(const float4*)(be1 + j * E2 + r);
    F4 bv; bv.f[0] = bv.f[1] = bv.f[2] = bv.f[3] = 0.0f;
    float avx = be1[j * E2 + rtc];
    float bvx = 0.0f;
    for (int d = 0; d < DIMF; d++) {
        float hv = h[d];
        F4 w1; w1.v = *(const float4*)(W + d * E2 + r);
        F4 w2; w2.v = *(const float4*)(W + (DIMF + d) * E2 + r);
#pragma unroll
        for (int i = 0; i < 4; i++) {
            av.f[i] = fmaf(hv, w1.f[i], av.f[i]);
            bv.f[i] = fmaf(hv, w2.f[i], bv.f[i]);
        }
        // tail (in-bounds for all lanes within this layer's W block; masked at store)
        avx = fmaf(hv, W[d * E2 + rt], avx);
        bvx = fmaf(hv, W[(DIMF + d) * E2 + rt], bvx);
    }
    *(float4*)(Ap + u * E2 + r) = av.v;
#pragma unroll
    for (int i = 0; i < 4; i++) BpT[(r + i) * PADU + u] = bv.f[i];
    if (lane < 4) {
        Ap[u * E2 + rt] = avx;
        BpT[rt * PADU + u] = bvx;
    }
}

// ---- per-pair edge MLP + m_i + coord update.
// One WAVE = one (receiver, 64-sender-tile) task; each lane owns exactly one
// pair. Weights via uniform (scalar-path) loads, B via coalesced transposed
// loads, A/receiver data via same-address L1 broadcast loads. Partial sums
// wave-reduced then atomicAdd'ed (mi/cout pre-initialized by k_ab).
__global__ __launch_bounds__(256) void k_pair(
    int j,
    const float* __restrict__ We1,   // wd/we rows
    const float* __restrict__ W2P,   // [3][260][20]
    const float* __restrict__ be2,
    const float* __restrict__ Wc1T,  // [3][68][20]
    const float* __restrict__ bc1,
    const float* __restrict__ Wc2,
    const float* __restrict__ bc2,
    const float* __restrict__ Ap,
    const float* __restrict__ BpT,   // [260][PADU]
    const float* __restrict__ cin, float* __restrict__ cout,
    float* __restrict__ mi, const int* __restrict__ sidx,
    const u64* __restrict__ ug2w) {
    int t = threadIdx.x;
    int wid = blockIdx.x * 4 + (t >> 6);
    if (wid >= TTOT) return;
    int lane = t & 63;

    int l, kl, off, a, tile;
    if (wid < T0TASK)       { l = 0; kl = K0; off = 0;  a = wid >> 3; tile = wid & 7; }
    else if (wid < T01TASK) { int w = wid - T0TASK;  l = 1; kl = K1; off = O1; a = w / NT1; tile = w - a * NT1; }
    else                    { int w = wid - T01TASK; l = 2; kl = K2; off = O2; a = w / NT2; tile = w - a * NT2; }
    int u = off + a;
    int b = tile * 64 + lane;
    float act = (b < kl) ? 1.0f : 0.0f;
    if (b >= kl) b = 0;
    int ub = off + b;

    int ia = sidx[l * NN + a];
    int ib = sidx[l * NN + b];
    float ef = (float)((ug2w[ia * 8 + (ib >> 6)] >> (ib & 63)) & 1ULL);
    F4 ca; ca.v = ((const float4*)cin)[u];
    F4 cb; cb.v = ((const float4*)cin)[ub];
    float rx = ca.f[0] - cb.f[0], ry = ca.f[1] - cb.f[1], rz = ca.f[2] - cb.f[2];
    float dd = rx * rx + ry * ry + rz * rz;

    const float* A  = Ap + u * E2;
    const float* WD = We1 + j * EINX * E2 + 128 * E2;
    const float* WE = WD + E2;
    const float* W2 = W2P + j * E2 * WPAD;

    float acc[MD];
#pragma unroll
    for (int o = 0; o < MD; o++) acc[o] = 0.0f;

    for (int r4 = 0; r4 < E2 / 4; r4++) {
        F4 a4, wd4, we4;
        a4.v  = *(const float4*)(A  + 4 * r4);
        wd4.v = *(const float4*)(WD + 4 * r4);
        we4.v = *(const float4*)(WE + 4 * r4);
#pragma unroll
        for (int e = 0; e < 4; e++) {
            int k = 4 * r4 + e;
            float bvv = BpT[k * PADU + ub];
            float s = siluf(fmaf(dd, wd4.f[e], fmaf(ef, we4.f[e], a4.f[e] + bvv)));
            const float* wr = W2 + k * WPAD;
#pragma unroll
            for (int o = 0; o < MD; o++) acc[o] = fmaf(s, wr[o], acc[o]);
        }
    }

    float m[MD];
#pragma unroll
    for (int o = 0; o < MD; o++) m[o] = siluf(acc[o] + be2[j * MD + o]);

    // coord MLP: cw = silu(m@Wc1+bc1)@Wc2+bc2
    float cw = bc2[j];
    const float* C1 = Wc1T + j * MH * WPAD;
    const float* C2 = Wc2 + j * MH;
    const float* B1 = bc1 + j * MH;
    for (int hh = 0; hh < MH; hh++) {
        const float* wr = C1 + hh * WPAD;
        float pre = B1[hh];
#pragma unroll
        for (int o = 0; o < MD; o++) pre = fmaf(m[o], wr[o], pre);
        cw = fmaf(siluf(pre), C2[hh], cw);
    }
    cw *= act;

    float v[20];
#pragma unroll
    for (int o = 0; o < MD; o++) v[o] = act * m[o];
    v[17] = cw * rx; v[18] = cw * ry; v[19] = cw * rz;
#pragma unroll
    for (int q = 0; q < 20; q++) {
        float x = v[q];
        for (int s = 32; s > 0; s >>= 1) x += __shfl_down(x, s);
        v[q] = x;
    }
    if (lane == 0) {
#pragma unroll
        for (int o = 0; o < MD; o++) atomicAdd(&mi[u * 20 + o], v[o]);
        atomicAdd(&cout[u * 4 + 0], v[17]);
        atomicAdd(&cout[u * 4 + 1], v[18]);
        atomicAdd(&cout[u * 4 + 2], v[19]);
    }
}

// ---- node MLP: hc = relu(2*hc + (silu([hc,m_i]@Wn1+bn1)@Wn2 + bn2))
__global__ __launch_bounds__(128) void k_node(
    int j, const float* __restrict__ Wn1, const float* __restrict__ bn1,
    const float* __restrict__ Wn2, const float* __restrict__ bn2,
    float* __restrict__ hc, const float* __restrict__ mi) {
    int u = blockIdx.x, t = threadIdx.x;
    __shared__ float sin_[DIMF + MD];
    __shared__ float st[NH1];
    if (t < DIMF) sin_[t] = hc[u * DIMF + t];
    else if (t < DIMF + MD) sin_[t] = mi[u * 20 + (t - DIMF)];
    __syncthreads();
    const float* W1 = Wn1 + j * (DIMF + MD) * NH1;
    float v = bn1[j * NH1 + t];
    for (int i = 0; i < DIMF + MD; i++) v = fmaf(sin_[i], W1[i * NH1 + t], v);
    st[t] = siluf(v);
    __syncthreads();
    if (t < DIMF) {
        const float* W2 = Wn2 + j * NH1 * DIMF;
        float h = bn2[j * DIMF + t];
        for (int i = 0; i < NH1; i++) h = fmaf(st[i], W2[i * DIMF + t], h);
        float hv = sin_[t];
        hc[u * DIMF + t] = fmaxf(0.0f, fmaf(2.0f, hv, h));
    }
}

// ---- scatter + 3-level max
__global__ void k_final(const float* __restrict__ hc, const int* __restrict__ rev,
                        float* __restrict__ out) {
    int gid = blockIdx.x * blockDim.x + threadIdx.x;
    if (gid >= NN * DIMF) return;
    int n = gid >> 6, d = gid & 63;
    float v = 0.0f;
    int a0 = rev[0 * NN + n];
    if (a0 >= 0) v = fmaxf(v, hc[(0 + a0) * DIMF + d]);
    int a1 = rev[1 * NN + n];
    if (a1 >= 0) v = fmaxf(v, hc[(O1 + a1) * DIMF + d]);
    int a2 = rev[2 * NN + n];
    if (a2 >= 0) v = fmaxf(v, hc[(O2 + a2) * DIMF + d]);
    out[gid] = v;
}

extern "C" void kernel_launch(void* const* d_in, const int* in_sizes, int n_in,
                              void* d_out, int out_size, void* d_ws, size_t ws_size,
                              hipStream_t stream) {
    (void)in_sizes; (void)n_in; (void)out_size; (void)ws_size;
    const float* feat = (const float*)d_in[0];
    const float* coor = (const float*)d_in[1];
    const float* edge = (const float*)d_in[2];
    const float* We1  = (const float*)d_in[3];
    const float* be1  = (const float*)d_in[4];
    const float* We2  = (const float*)d_in[5];
    const float* be2  = (const float*)d_in[6];
    const float* Wc1  = (const float*)d_in[7];
    const float* bc1  = (const float*)d_in[8];
    const float* Wc2  = (const float*)d_in[9];
    const float* bc2  = (const float*)d_in[10];
    const float* Wn1  = (const float*)d_in[11];
    const float* bn1  = (const float*)d_in[12];
    const float* Wn2  = (const float*)d_in[13];
    const float* bn2  = (const float*)d_in[14];
    const float* wp   = (const float*)d_in[15];
    const float* bp   = (const float*)d_in[16];
    float* out = (float*)d_out;

    char* wsb = (char*)d_ws;
    u64*   ugw    = (u64*)(wsb + 0);        // 32768
    u64*   ug2w   = (u64*)(wsb + 32768);    // 32768
    float* scores = (float*)(wsb + 65536);  // 6144
    float* svals  = (float*)(wsb + 71680);  // 6144
    int*   sidx   = (int*)(wsb + 77824);    // 6144
    int*   rev    = (int*)(wsb + 83968);    // 6144
    float* c0     = (float*)(wsb + 90112);  // 18176
    float* c1     = (float*)(wsb + 108288); // 18176
    float* mi     = (float*)(wsb + 126464); // 90112
    float* hc     = (float*)(wsb + 216576); // 288256
    float* Ap     = (float*)(wsb + 504832); // 1170176
    float* BpT    = (float*)(wsb + 1675008);// 1173504 (260*1128*4)
    float* W2P    = (float*)(wsb + 2848512);// 62464   (3*260*20*4)
    float* Wc1T   = (float*)(wsb + 2910976);// 16320   (3*68*20*4)  end ~2.93 MB

    k_prep<<<8, 256, 0, stream>>>(We2, Wc1, W2P, Wc1T);
    k_ug_build<<<NN, 64, 0, stream>>>(edge, ugw);
    k_ug2<<<16, 256, 0, stream>>>(ugw, ug2w);
    k_scores<<<6, 256, 0, stream>>>(feat, wp, bp, scores);
    k_sort<<<3, NN, 0, stream>>>(scores, svals, sidx, rev);
    k_gather<<<KT, 64, 0, stream>>>(feat, coor, svals, sidx, hc, c0);
    for (int j = 0; j < 3; j++) {
        const float* ci = (j & 1) ? c1 : c0;
        float* co = (j & 1) ? c0 : c1;
        k_ab<<<(KT + 3) / 4, 256, 0, stream>>>(j, We1, be1, hc, Ap, BpT, ci, co, mi);
        k_pair<<<PAIRBLOCKS, 256, 0, stream>>>(j, We1, W2P, be2, Wc1T, bc1, Wc2, bc2,
                                               Ap, BpT, ci, co, mi, sidx, ug2w);
        k_node<<<KT, 128, 0, stream>>>(j, Wn1, bn1, Wn2, bn2, hc, mi);
    }
    k_final<<<(NN * DIMF) / 256, 256, 0, stream>>>(hc, rev, out);
}

// Round 4
// 499.147 us; speedup vs baseline: 1.7724x; 1.3943x over previous
//
#include <hip/hip_runtime.h>

typedef unsigned long long u64;
typedef unsigned int u32;
typedef unsigned short u16;

#define NN   512
#define DIMF 64
#define E2   260
#define KPAD 272
#define MD   17
#define MH   68
#define NH1  128
#define K0   460
#define K1   358
#define K2   307
#define KT   1125
#define O1   460
#define O2   818
#define PADU 1152
#define AS   272
// 32-sender tiles per receiver
#define NT0  15
#define NT1  12
#define NT2  10
#define T0T   (K0*NT0)          // 6900
#define T01T  (T0T + K1*NT1)    // 11196
#define TTOT  (T01T + K2*NT2)   // 14266
#define PBLK  ((TTOT+3)/4)      // 3567

typedef __attribute__((ext_vector_type(8)))  short short8;
typedef __attribute__((ext_vector_type(16))) float f32x16;

union SF  { int4 i4; u16 us[8]; short8 v; };
union F4U { float4 v; float f[4]; };

__device__ __forceinline__ float fast_exp2(float x){
#if __has_builtin(__builtin_amdgcn_exp2f)
    return __builtin_amdgcn_exp2f(x);
#else
    return __expf(x * 0.6931471805599453f);
#endif
}
__device__ __forceinline__ float fast_rcp(float x){
#if __has_builtin(__builtin_amdgcn_rcpf)
    return __builtin_amdgcn_rcpf(x);
#else
    return __fdividef(1.0f, x);
#endif
}
__device__ __forceinline__ float siluf(float x){
    return x * fast_rcp(1.0f + fast_exp2(x * -1.4426950408889634f));
}
__device__ __forceinline__ float sigf(float x){
    return fast_rcp(1.0f + fast_exp2(x * -1.4426950408889634f));
}
__device__ __forceinline__ u16 bf16_rne(float f){
    u32 u = __float_as_uint(f);
    u += 0x7FFFu + ((u >> 16) & 1u);
    return (u16)(u >> 16);
}
__device__ __forceinline__ float bf16f(u16 h){
    return __uint_as_float(((u32)h) << 16);
}
__device__ __forceinline__ void lgkm_wait(){
#if __has_builtin(__builtin_amdgcn_s_waitcnt)
    __builtin_amdgcn_s_waitcnt(0xC07F);   // lgkmcnt(0), vmcnt/expcnt = max
#endif
}

// ============ fused prep: ug bitmasks + pooling scores + weight fragments ===
__global__ __launch_bounds__(256) void k_pre(
    const float* __restrict__ edge, const float* __restrict__ feat,
    const float* __restrict__ wp, const float* __restrict__ bp,
    const float* __restrict__ We2, const float* __restrict__ Wc1,
    const float* __restrict__ We1, const float* __restrict__ be2,
    const float* __restrict__ bc1, const float* __restrict__ Wc2,
    u64* __restrict__ ugw, float* __restrict__ scores,
    u16* __restrict__ W2fH, u16* __restrict__ W2fL, u16* __restrict__ Wc1f,
    float* __restrict__ wdP, float* __restrict__ weP, float* __restrict__ be2P,
    float* __restrict__ bc1P, float* __restrict__ Wc2P){
    int blk = blockIdx.x, t = threadIdx.x;
    if (blk < 128){                      // ug row bitmasks, 4 rows/block
        int i = blk*4 + (t>>6); int lane = t&63;
        const float* row = edge + (size_t)i*NN;
        for (int w = 0; w < 8; w++){
            u64 m = __ballot(row[w*64+lane] != 0.0f);
            if (lane == 0) ugw[i*8+w] = m;
        }
        return;
    }
    if (blk < 134){                      // pooling scores
        int gid = (blk-128)*256 + t; if (gid >= 3*NN) return;
        int l = gid>>9, n = gid&511;
        float s = bp[l];
        for (int d = 0; d < DIMF; d++) s = fmaf(feat[n*DIMF+d], wp[l*DIMF+d], s);
        scores[gid] = sigf(s);
        return;
    }
    int idx = (blk-134)*256 + t;
    if (idx < 26112){                    // We2 frags hi/lo: [jl][c17][lane][8]
        int e = idx & 7, lane = (idx>>3)&63, c = (idx>>9)%17, jl = idx/8704;
        int q = lane>>5, n = lane&31;
        int k = c*16 + q*8 + e;
        float v = (k < E2 && n < MD) ? We2[jl*E2*MD + k*MD + n] : 0.0f;
        u16 hi = bf16_rne(v);
        W2fH[idx] = hi;
        W2fL[idx] = bf16_rne(v - bf16f(hi));
        return;
    }
    idx -= 26112;
    if (idx < 9216){                     // Wc1 frags: [jl][T3][c2][lane][8]
        int e = idx & 7, lane = (idx>>3)&63, c2 = (idx>>9)&1, T = (idx>>10)%3, jl = idx/3072;
        int q = lane>>5, n = lane&31;
        int o = c2*16 + q*8 + e, h = T*32 + n;
        float v = (o < MD && h < MH) ? Wc1[jl*MD*MH + o*MH + h] : 0.0f;
        Wc1f[idx] = bf16_rne(v);
        return;
    }
    idx -= 9216;
    if (idx < 816){ int jl = idx/KPAD, k = idx%KPAD;
        wdP[idx] = (k < E2) ? We1[jl*130*E2 + 128*E2 + k] : 0.0f; return; }
    idx -= 816;
    if (idx < 816){ int jl = idx/KPAD, k = idx%KPAD;
        weP[idx] = (k < E2) ? We1[jl*130*E2 + 129*E2 + k] : 0.0f; return; }
    idx -= 816;
    if (idx < 96){ int jl = idx/32, o = idx%32;
        be2P[idx] = (o < MD) ? be2[jl*MD+o] : 0.0f; return; }
    idx -= 96;
    if (idx < 288){ int jl = idx/96, h = idx%96;
        bc1P[idx] = (h < MH) ? bc1[jl*MH+h] : 0.0f; return; }
    idx -= 288;
    if (idx < 288){ int jl = idx/96, h = idx%96;
        Wc2P[idx] = (h < MH) ? Wc2[jl*MH+h] : 0.0f; return; }
}

// ============ fused: bitonic sort (3 blocks) + ug2 boolean matmul (8 blocks) =
__global__ __launch_bounds__(512) void k_sortug2(
    const float* __restrict__ scores, const u64* __restrict__ ugw,
    float* __restrict__ svals, int* __restrict__ sidx, int* __restrict__ rev,
    u64* __restrict__ ug2w){
    int blk = blockIdx.x, t = threadIdx.x;
    if (blk < 3){
        int l = blk;
        __shared__ float sk[NN];
        __shared__ int   si[NN];
        sk[t] = scores[l*NN+t]; si[t] = t; rev[l*NN+t] = -1;
        __syncthreads();
        for (int k = 2; k <= NN; k <<= 1){
            for (int jj = k>>1; jj > 0; jj >>= 1){
                int p = t ^ jj;
                if (p > t){
                    float ka = sk[t], kb = sk[p];
                    int ia = si[t], ib = si[p];
                    bool before = (ka > kb) || (ka == kb && ia < ib);
                    bool sw = ((t & k) == 0) ? (!before) : before;
                    if (sw){ sk[t]=kb; sk[p]=ka; si[t]=ib; si[p]=ia; }
                }
                __syncthreads();
            }
        }
        svals[l*NN+t] = sk[t]; sidx[l*NN+t] = si[t];
        int kcnt = (l==0)?K0:(l==1)?K1:K2;
        if (t < kcnt) rev[l*NN + si[t]] = t;
    } else {
        int gid = (blk-3)*512 + t;       // 4096 total
        int i = gid>>3, w = gid&7;
        u64 rm[8];
#pragma unroll
        for (int q = 0; q < 8; q++) rm[q] = ugw[i*8+q];
        u64 acc = 0;
        for (int k = 0; k < NN; k++)
            if ((rm[k>>6] >> (k&63)) & 1ULL) acc |= ugw[k*8+w];
        ug2w[i*8+w] = acc;
    }
}

// ============ A/B precompute (shared by k_gab / k_nodeab) ====================
__device__ __forceinline__ void ab_comp(int jl, const float* __restrict__ We1,
                                        const float* __restrict__ be1, float hval,
                                        int u, int lane,
                                        float* __restrict__ Ap, float* __restrict__ BpT){
    const float* W = We1 + jl*130*E2;
    int r  = 4*lane;
    int rt = 256 + lane;
    int rtc = (lane < 4) ? rt : 0;
    F4U av; av.v = *(const float4*)(be1 + jl*E2 + r);
    F4U bv; bv.f[0]=bv.f[1]=bv.f[2]=bv.f[3]=0.0f;
    float avx = be1[jl*E2 + rtc];
    float bvx = 0.0f;
    for (int d = 0; d < DIMF; d++){
        float hv = __shfl(hval, d);
        F4U w1; w1.v = *(const float4*)(W + d*E2 + r);
        F4U w2; w2.v = *(const float4*)(W + (DIMF+d)*E2 + r);
#pragma unroll
        for (int i = 0; i < 4; i++){
            av.f[i] = fmaf(hv, w1.f[i], av.f[i]);
            bv.f[i] = fmaf(hv, w2.f[i], bv.f[i]);
        }
        avx = fmaf(hv, W[d*E2 + rt], avx);
        bvx = fmaf(hv, W[(DIMF+d)*E2 + rt], bvx);
    }
    *(float4*)(Ap + u*AS + r) = av.v;
#pragma unroll
    for (int i = 0; i < 4; i++) BpT[(r+i)*PADU + u] = bv.f[i];
    if (lane < 4){ Ap[u*AS + rt] = avx; BpT[rt*PADU + u] = bvx; }
}

// ============ gather + AB(layer0) + init mi/c0/c1 ===========================
__global__ __launch_bounds__(256) void k_gab(
    const float* __restrict__ feat, const float* __restrict__ coor,
    const float* __restrict__ svals, const int* __restrict__ sidx,
    const float* __restrict__ We1, const float* __restrict__ be1,
    float* __restrict__ hc, float* __restrict__ c0, float* __restrict__ c1,
    float* __restrict__ mi, float* __restrict__ Ap, float* __restrict__ BpT){
    int t = threadIdx.x; int u = blockIdx.x*4 + (t>>6); if (u >= KT) return;
    int lane = t&63;
    int l = (u<K0)?0:(u<O2)?1:2;
    int a = u - ((l==0)?0:(l==1)?O1:O2);
    int org = sidx[l*NN+a];
    float val = svals[l*NN+a];
    float hval = feat[org*DIMF+lane]*val;
    hc[u*DIMF+lane] = hval;
    if (lane < 3){ float c = coor[org*3+lane]; c0[u*4+lane]=c; c1[u*4+lane]=c; }
    if (lane == 3){ c0[u*4+3]=0.0f; c1[u*4+3]=0.0f; }
    if (lane < 20) mi[u*20+lane] = 0.0f;
    ab_comp(0, We1, be1, hval, u, lane, Ap, BpT);
}

// ============ per-pair edge MLP via MFMA =====================================
// wave = (receiver u, 32-sender tile). Lane computes silu row s for pair
// (lane&31) at k=(lane>>5)*8+j  == MFMA A-frag layout. D = s @ We2 via
// 32x32x16 bf16 MFMA (3-term hi/lo split). m_i: reg-sum + shfl_xor(32) +
// atomicAdd. m -> LDS -> A-frag -> MFMA vs Wc1 frags -> silu -> Wc2 ->
// coord delta folded into lane-local sums + one 64-lane reduce.
__global__ __launch_bounds__(256) void k_pair(
    int jl, int docw,
    const float* __restrict__ Ap, const float* __restrict__ BpT,
    const u16* __restrict__ W2fH, const u16* __restrict__ W2fL,
    const u16* __restrict__ Wc1f,
    const float* __restrict__ wdP, const float* __restrict__ weP,
    const float* __restrict__ be2P, const float* __restrict__ bc1P,
    const float* __restrict__ Wc2P, const float* __restrict__ bc2,
    const float* __restrict__ cin, float* __restrict__ cout,
    float* __restrict__ mi, const int* __restrict__ sidx,
    const u64* __restrict__ ug2w){
    __shared__ __align__(16) u16 smem[4*32*40];
    int t = threadIdx.x;
    int wid = blockIdx.x*4 + (t>>6);
    if (wid >= TTOT) return;
    int lane = t&63, n = lane&31, q = lane>>5;

    int l, kl, off, a, tile;
    if (wid < T0T)       { l=0; kl=K0; off=0;  a = wid/NT0;  tile = wid - a*NT0; }
    else if (wid < T01T) { int w = wid-T0T;  l=1; kl=K1; off=O1; a = w/NT1; tile = w - a*NT1; }
    else                 { int w = wid-T01T; l=2; kl=K2; off=O2; a = w/NT2; tile = w - a*NT2; }
    int u  = off + a;
    int b  = tile*32 + n;
    int ub = off + b;

    int ia = sidx[l*NN+a], ib = sidx[l*NN+b];
    float ef = (float)((ug2w[ia*8 + (ib>>6)] >> (ib&63)) & 1ULL);
    F4U ca; ca.v = ((const float4*)cin)[u];
    F4U cb; cb.v = ((const float4*)cin)[ub];
    float rx = ca.f[0]-cb.f[0], ry = ca.f[1]-cb.f[1], rz = ca.f[2]-cb.f[2];
    float dd = rx*rx + ry*ry + rz*rz;

    const float* Au = Ap  + u*AS;
    const float* wd = wdP + jl*KPAD;
    const float* we = weP + jl*KPAD;
    const u16*   WH = W2fH + jl*8704;
    const u16*   WL = W2fL + jl*8704;

    f32x16 acc;
#pragma unroll
    for (int r = 0; r < 16; r++) acc[r] = 0.0f;

    for (int c = 0; c < 17; c++){
        int kb = c*16 + q*8;
        F4U a0,a1,w0,w1,e0,e1;
        a0.v = *(const float4*)(Au+kb); a1.v = *(const float4*)(Au+kb+4);
        w0.v = *(const float4*)(wd+kb); w1.v = *(const float4*)(wd+kb+4);
        e0.v = *(const float4*)(we+kb); e1.v = *(const float4*)(we+kb+4);
        SF shi, slo;
#pragma unroll
        for (int e = 0; e < 8; e++){
            float af = (e<4)? a0.f[e] : a1.f[e-4];
            float wf = (e<4)? w0.f[e] : w1.f[e-4];
            float ff = (e<4)? e0.f[e] : e1.f[e-4];
            float bvv = BpT[(kb+e)*PADU + ub];
            float pre = fmaf(dd, wf, fmaf(ef, ff, af + bvv));
            float s = siluf(pre);
            u32 sb = __float_as_uint(s);
            shi.us[e] = (u16)(sb >> 16);
            float lof = s - __uint_as_float(sb & 0xFFFF0000u);
            slo.us[e] = (u16)(__float_as_uint(lof) >> 16);
        }
        SF wh, wl;
        wh.i4 = *(const int4*)(WH + c*512 + lane*8);
        wl.i4 = *(const int4*)(WL + c*512 + lane*8);
        acc = __builtin_amdgcn_mfma_f32_32x32x16_bf16(shi.v, wh.v, acc, 0, 0, 0);
        acc = __builtin_amdgcn_mfma_f32_32x32x16_bf16(slo.v, wh.v, acc, 0, 0, 0);
        acc = __builtin_amdgcn_mfma_f32_32x32x16_bf16(shi.v, wl.v, acc, 0, 0, 0);
    }

    // ---- m = silu(acc + be2); masked m_i sum (rows = pairs, col = o = n)
    float be2v = be2P[jl*32 + n];
    float msum = 0.0f;
    float mv[16];
#pragma unroll
    for (int r = 0; r < 16; r++){
        int row  = (r&3) + 8*(r>>2) + 4*q;
        int brow = tile*32 + row;
        float mm = siluf(acc[r] + be2v);
        mm = (brow < kl) ? mm : 0.0f;
        mv[r] = mm; msum += mm;
    }
    msum += __shfl_xor(msum, 32);
    if (lane < MD) atomicAdd(&mi[u*20+lane], msum);

    if (!docw) return;

    // ---- repack m (bf16) into A-frag layout via wave-private LDS
    u16* lds = smem + (t>>6)*1280;
#pragma unroll
    for (int r = 0; r < 16; r++){
        int row = (r&3) + 8*(r>>2) + 4*q;
        lds[row*40 + n] = bf16_rne(mv[r]);
    }
    lgkm_wait();
    const char* lbase = (const char*)lds;
    SF af0, af1;
    af0.i4 = *(const int4*)(lbase + n*80 +      q*16);
    af1.i4 = *(const int4*)(lbase + n*80 + 32 + q*16);

    // ---- coord MLP: P = m @ Wc1 (3 h-tiles), cw = silu(P)+Wc2 folded
    const u16* WC = Wc1f + jl*3072;
    float cwp[16];
#pragma unroll
    for (int r = 0; r < 16; r++) cwp[r] = 0.0f;
    for (int T = 0; T < 3; T++){
        SF b0, b1;
        b0.i4 = *(const int4*)(WC + T*1024       + lane*8);
        b1.i4 = *(const int4*)(WC + T*1024 + 512 + lane*8);
        f32x16 p2;
#pragma unroll
        for (int r = 0; r < 16; r++) p2[r] = 0.0f;
        p2 = __builtin_amdgcn_mfma_f32_32x32x16_bf16(af0.v, b0.v, p2, 0, 0, 0);
        p2 = __builtin_amdgcn_mfma_f32_32x32x16_bf16(af1.v, b1.v, p2, 0, 0, 0);
        float bc1v = bc1P[jl*96 + T*32 + n];
        float wc2v = Wc2P[jl*96 + T*32 + n];
#pragma unroll
        for (int r = 0; r < 16; r++)
            cwp[r] = fmaf(siluf(p2[r] + bc1v), wc2v, cwp[r]);
    }
    float bc2v = bc2[jl];
    float dx = 0.0f, dy = 0.0f, dz = 0.0f;
#pragma unroll
    for (int r = 0; r < 16; r++){
        int row  = (r&3) + 8*(r>>2) + 4*q;
        int brow = tile*32 + row;
        F4U cbr; cbr.v = ((const float4*)cin)[off + brow];
        float cw = cwp[r] + ((n == 0) ? bc2v : 0.0f);
        cw = (brow < kl) ? cw : 0.0f;
        dx = fmaf(cw, ca.f[0]-cbr.f[0], dx);
        dy = fmaf(cw, ca.f[1]-cbr.f[1], dy);
        dz = fmaf(cw, ca.f[2]-cbr.f[2], dz);
    }
#pragma unroll
    for (int s = 1; s < 64; s <<= 1){
        dx += __shfl_xor(dx, s); dy += __shfl_xor(dy, s); dz += __shfl_xor(dz, s);
    }
    if (lane == 0){
        atomicAdd(&cout[u*4+0], dx);
        atomicAdd(&cout[u*4+1], dy);
        atomicAdd(&cout[u*4+2], dz);
    }
}

// ============ node MLP + (optionally) AB for next layer + inits ==============
__global__ __launch_bounds__(256) void k_nodeab(
    int jl, int donext, int docopy,
    const float* __restrict__ Wn1, const float* __restrict__ bn1,
    const float* __restrict__ Wn2, const float* __restrict__ bn2,
    const float* __restrict__ We1, const float* __restrict__ be1,
    float* __restrict__ hc, float* __restrict__ mi,
    const float* __restrict__ ccur, float* __restrict__ cnext,
    float* __restrict__ Ap, float* __restrict__ BpT){
    int t = threadIdx.x; int u = blockIdx.x*4 + (t>>6); if (u >= KT) return;
    int lane = t&63;
    float hval = hc[u*DIMF+lane];
    float mval = (lane < MD) ? mi[u*20+lane] : 0.0f;
    const float* W1 = Wn1 + jl*(DIMF+MD)*NH1;
    float v0 = bn1[jl*NH1+lane], v1 = bn1[jl*NH1+lane+64];
    for (int d = 0; d < DIMF; d++){
        float x = __shfl(hval, d);
        v0 = fmaf(x, W1[d*NH1+lane],    v0);
        v1 = fmaf(x, W1[d*NH1+lane+64], v1);
    }
    for (int d = 0; d < MD; d++){
        float x = __shfl(mval, d);
        v0 = fmaf(x, W1[(DIMF+d)*NH1+lane],    v0);
        v1 = fmaf(x, W1[(DIMF+d)*NH1+lane+64], v1);
    }
    float s0 = siluf(v0), s1 = siluf(v1);
    const float* W2 = Wn2 + jl*NH1*DIMF;
    float h = bn2[jl*DIMF+lane];
    for (int i = 0; i < 64; i++) h = fmaf(__shfl(s0, i), W2[i*DIMF+lane], h);
    for (int i = 0; i < 64; i++) h = fmaf(__shfl(s1, i), W2[(64+i)*DIMF+lane], h);
    float hn = fmaxf(0.0f, fmaf(2.0f, hval, h));
    hc[u*DIMF+lane] = hn;
    if (donext){
        if (lane < 20) mi[u*20+lane] = 0.0f;
        if (docopy && lane < 4) cnext[u*4+lane] = ccur[u*4+lane];
        ab_comp(jl+1, We1, be1, hn, u, lane, Ap, BpT);
    }
}

// ============ scatter + 3-level max =========================================
__global__ void k_final(const float* __restrict__ hc, const int* __restrict__ rev,
                        float* __restrict__ out){
    int gid = blockIdx.x*blockDim.x + threadIdx.x;
    if (gid >= NN*DIMF) return;
    int nn = gid>>6, d = gid&63;
    float v = 0.0f;
    int a0 = rev[0*NN+nn]; if (a0 >= 0) v = fmaxf(v, hc[(0  + a0)*DIMF + d]);
    int a1 = rev[1*NN+nn]; if (a1 >= 0) v = fmaxf(v, hc[(O1 + a1)*DIMF + d]);
    int a2 = rev[2*NN+nn]; if (a2 >= 0) v = fmaxf(v, hc[(O2 + a2)*DIMF + d]);
    out[gid] = v;
}

extern "C" void kernel_launch(void* const* d_in, const int* in_sizes, int n_in,
                              void* d_out, int out_size, void* d_ws, size_t ws_size,
                              hipStream_t stream) {
    (void)in_sizes; (void)n_in; (void)out_size; (void)ws_size;
    const float* feat = (const float*)d_in[0];
    const float* coor = (const float*)d_in[1];
    const float* edge = (const float*)d_in[2];
    const float* We1  = (const float*)d_in[3];
    const float* be1  = (const float*)d_in[4];
    const float* We2  = (const float*)d_in[5];
    const float* be2  = (const float*)d_in[6];
    const float* Wc1  = (const float*)d_in[7];
    const float* bc1  = (const float*)d_in[8];
    const float* Wc2  = (const float*)d_in[9];
    const float* bc2  = (const float*)d_in[10];
    const float* Wn1  = (const float*)d_in[11];
    const float* bn1  = (const float*)d_in[12];
    const float* Wn2  = (const float*)d_in[13];
    const float* bn2  = (const float*)d_in[14];
    const float* wp   = (const float*)d_in[15];
    const float* bp   = (const float*)d_in[16];
    float* out = (float*)d_out;

    char* wsb = (char*)d_ws;
    u64*   ugw    = (u64*)  (wsb + 0);         // 32768
    u64*   ug2w   = (u64*)  (wsb + 32768);     // 32768
    float* scores = (float*)(wsb + 65536);     // 6144
    float* svals  = (float*)(wsb + 71680);     // 6144
    int*   sidx   = (int*)  (wsb + 77824);     // 6144
    int*   rev    = (int*)  (wsb + 83968);     // 6144
    float* c0     = (float*)(wsb + 90112);     // 18432
    float* c1     = (float*)(wsb + 108544);    // 18432
    float* mi     = (float*)(wsb + 126976);    // 90112
    float* hc     = (float*)(wsb + 217088);    // 288256
    float* Ap     = (float*)(wsb + 505344);    // 1224192
    float* BpT    = (float*)(wsb + 1729536);   // 1253376
    u16*   W2fH   = (u16*)  (wsb + 2982912);   // 52224
    u16*   W2fL   = (u16*)  (wsb + 3035136);   // 52224
    u16*   Wc1f   = (u16*)  (wsb + 3087360);   // 18432
    float* wdP    = (float*)(wsb + 3105792);   // 3328
    float* weP    = (float*)(wsb + 3109120);   // 3328
    float* be2P   = (float*)(wsb + 3112448);   // 384
    float* bc1P   = (float*)(wsb + 3112832);   // 1152
    float* Wc2P   = (float*)(wsb + 3113984);   // 1152  (end ~3.12 MB)

    k_pre<<<281, 256, 0, stream>>>(edge, feat, wp, bp, We2, Wc1, We1, be2, bc1, Wc2,
                                   ugw, scores, W2fH, W2fL, Wc1f,
                                   wdP, weP, be2P, bc1P, Wc2P);
    k_sortug2<<<11, 512, 0, stream>>>(scores, ugw, svals, sidx, rev, ug2w);
    k_gab<<<282, 256, 0, stream>>>(feat, coor, svals, sidx, We1, be1,
                                   hc, c0, c1, mi, Ap, BpT);
    // layer 0: cin=c0, cout=c1
    k_pair<<<PBLK, 256, 0, stream>>>(0, 1, Ap, BpT, W2fH, W2fL, Wc1f,
                                     wdP, weP, be2P, bc1P, Wc2P, bc2,
                                     c0, c1, mi, sidx, ug2w);
    k_nodeab<<<282, 256, 0, stream>>>(0, 1, 1, Wn1, bn1, Wn2, bn2, We1, be1,
                                      hc, mi, c1, c0, Ap, BpT);
    // layer 1: cin=c1, cout=c0 (pre-initialized to c1 by k_nodeab)
    k_pair<<<PBLK, 256, 0, stream>>>(1, 1, Ap, BpT, W2fH, W2fL, Wc1f,
                                     wdP, weP, be2P, bc1P, Wc2P, bc2,
                                     c1, c0, mi, sidx, ug2w);
    k_nodeab<<<282, 256, 0, stream>>>(1, 1, 0, Wn1, bn1, Wn2, bn2, We1, be1,
                                      hc, mi, c0, c1, Ap, BpT);
    // layer 2: coords output unused -> skip coord MLP entirely
    k_pair<<<PBLK, 256, 0, stream>>>(2, 0, Ap, BpT, W2fH, W2fL, Wc1f,
                                     wdP, weP, be2P, bc1P, Wc2P, bc2,
                                     c0, c1, mi, sidx, ug2w);
    k_nodeab<<<282, 256, 0, stream>>>(2, 0, 0, Wn1, bn1, Wn2, bn2, We1, be1,
                                      hc, mi, c0, c1, Ap, BpT);
    k_final<<<128, 256, 0, stream>>>(hc, rev, out);
}

// Round 6
// 448.360 us; speedup vs baseline: 1.9732x; 1.1133x over previous
//
#include <hip/hip_runtime.h>
#include <hip/hip_bf16.h>

typedef unsigned long long u64;
typedef unsigned int u32;
typedef unsigned short u16;

#define NN   512
#define DIMF 64
#define E2   260
#define KPAD 272
#define MD   17
#define MH   68
#define NH1  128
#define K0   460
#define K1   358
#define K2   307
#define KT   1125
#define O1   460
#define O2   818
#define PADU 1152
#define AS   272
// 64-sender tiles per receiver, one wave each (2 MFMA acc sets of 32)
#define NT0  8
#define NT1  6
#define NT2  5
#define T0T   (K0*NT0)          // 3680
#define T01T  (T0T + K1*NT1)    // 5828
#define TTOT  (T01T + K2*NT2)   // 7363
#define PBLK  ((TTOT+3)/4)      // 1841
#define MSTR  40                // u16 stride of m-repack rows (80 B, 16B-aligned)
#define WVLDS 5120              // per-wave LDS scratch bytes

typedef __attribute__((ext_vector_type(8)))  short short8;
typedef __attribute__((ext_vector_type(16))) float f32x16;

union SF  { int4 i4; u16 us[8]; u32 w[4]; short8 v; };
union F4U { float4 v; float f[4]; };

__device__ __forceinline__ float fast_exp2(float x){
#if __has_builtin(__builtin_amdgcn_exp2f)
    return __builtin_amdgcn_exp2f(x);
#else
    return __expf(x * 0.6931471805599453f);
#endif
}
__device__ __forceinline__ float fast_rcp(float x){
#if __has_builtin(__builtin_amdgcn_rcpf)
    return __builtin_amdgcn_rcpf(x);
#else
    return __fdividef(1.0f, x);
#endif
}
__device__ __forceinline__ float siluf(float x){
    return x * fast_rcp(1.0f + fast_exp2(x * -1.4426950408889634f));
}
__device__ __forceinline__ float sigf(float x){
    return fast_rcp(1.0f + fast_exp2(x * -1.4426950408889634f));
}
__device__ __forceinline__ u16 bf16_rne(float f){
    u32 u = __float_as_uint(f);
    u += 0x7FFFu + ((u >> 16) & 1u);
    return (u16)(u >> 16);
}
__device__ __forceinline__ float bf16f(u16 h){
    return __uint_as_float(((u32)h) << 16);
}
__device__ __forceinline__ u32 pk_bf16(float x, float y){
    float2 f2; f2.x = x; f2.y = y;
    __hip_bfloat162 h = __float22bfloat162_rn(f2);
    union { __hip_bfloat162 b; u32 u; } cv; cv.b = h;
    return cv.u;
}
__device__ __forceinline__ void lgkm_wait(){
#if __has_builtin(__builtin_amdgcn_s_waitcnt)
    __builtin_amdgcn_s_waitcnt(0xC07F);   // lgkmcnt(0)
#endif
}

// ============ fused prep: ug bitmasks + pooling scores + weight fragments ===
__global__ __launch_bounds__(256) void k_pre(
    const float* __restrict__ edge, const float* __restrict__ feat,
    const float* __restrict__ wp, const float* __restrict__ bp,
    const float* __restrict__ We2, const float* __restrict__ Wc1,
    const float* __restrict__ We1, const float* __restrict__ be2,
    const float* __restrict__ bc1, const float* __restrict__ Wc2,
    u64* __restrict__ ugw, float* __restrict__ scores,
    u16* __restrict__ W2f, u16* __restrict__ Wc1f,
    float* __restrict__ wdP, float* __restrict__ weP, float* __restrict__ be2P,
    float* __restrict__ bc1P, float* __restrict__ Wc2P){
    int blk = blockIdx.x, t = threadIdx.x;
    if (blk < 128){                      // ug row bitmasks, 4 rows/block
        int i = blk*4 + (t>>6); int lane = t&63;
        const float* row = edge + (size_t)i*NN;
        for (int w = 0; w < 8; w++){
            u64 m = __ballot(row[w*64+lane] != 0.0f);
            if (lane == 0) ugw[i*8+w] = m;
        }
        return;
    }
    if (blk < 134){                      // pooling scores
        int gid = (blk-128)*256 + t; if (gid >= 3*NN) return;
        int l = gid>>9, n = gid&511;
        float s = bp[l];
        for (int d = 0; d < DIMF; d++) s = fmaf(feat[n*DIMF+d], wp[l*DIMF+d], s);
        scores[gid] = sigf(s);
        return;
    }
    int idx = (blk-134)*256 + t;
    if (idx < 52224){                    // We2 frags interleaved hi/lo: [jl][c17][hl2][lane][8]
        int e = idx&7, lane = (idx>>3)&63, hl = (idx>>9)&1, c = (idx>>10)%17, jl = idx/17408;
        int q = lane>>5, nn = lane&31;
        int k = c*16 + q*8 + e;
        float v = (k < E2 && nn < MD) ? We2[jl*E2*MD + k*MD + nn] : 0.0f;
        u16 hi = bf16_rne(v);
        W2f[idx] = hl ? bf16_rne(v - bf16f(hi)) : hi;
        return;
    }
    idx -= 52224;
    if (idx < 9216){                     // Wc1 frags: [jl][T3][c2][lane][8]
        int e = idx & 7, lane = (idx>>3)&63, c2 = (idx>>9)&1, T = (idx>>10)%3, jl = idx/3072;
        int q = lane>>5, nn = lane&31;
        int o = c2*16 + q*8 + e, h = T*32 + nn;
        float v = (o < MD && h < MH) ? Wc1[jl*MD*MH + o*MH + h] : 0.0f;
        Wc1f[idx] = bf16_rne(v);
        return;
    }
    idx -= 9216;
    if (idx < 816){ int jl = idx/KPAD, k = idx%KPAD;
        wdP[idx] = (k < E2) ? We1[jl*130*E2 + 128*E2 + k] : 0.0f; return; }
    idx -= 816;
    if (idx < 816){ int jl = idx/KPAD, k = idx%KPAD;
        weP[idx] = (k < E2) ? We1[jl*130*E2 + 129*E2 + k] : 0.0f; return; }
    idx -= 816;
    if (idx < 96){ int jl = idx/32, o = idx%32;
        be2P[idx] = (o < MD) ? be2[jl*MD+o] : 0.0f; return; }
    idx -= 96;
    if (idx < 288){ int jl = idx/96, h = idx%96;
        bc1P[idx] = (h < MH) ? bc1[jl*MH+h] : 0.0f; return; }
    idx -= 288;
    if (idx < 288){ int jl = idx/96, h = idx%96;
        Wc2P[idx] = (h < MH) ? Wc2[jl*MH+h] : 0.0f; return; }
}

// ============ fused: bitonic sort (3 blocks) + ug2 boolean matmul (8 blocks) =
__global__ __launch_bounds__(512) void k_sortug2(
    const float* __restrict__ scores, const u64* __restrict__ ugw,
    float* __restrict__ svals, int* __restrict__ sidx, int* __restrict__ rev,
    u64* __restrict__ ug2w){
    int blk = blockIdx.x, t = threadIdx.x;
    if (blk < 3){
        int l = blk;
        __shared__ float sk[NN];
        __shared__ int   si[NN];
        sk[t] = scores[l*NN+t]; si[t] = t; rev[l*NN+t] = -1;
        __syncthreads();
        for (int k = 2; k <= NN; k <<= 1){
            for (int jj = k>>1; jj > 0; jj >>= 1){
                int p = t ^ jj;
                if (p > t){
                    float ka = sk[t], kb = sk[p];
                    int ia = si[t], ib = si[p];
                    bool before = (ka > kb) || (ka == kb && ia < ib);
                    bool sw = ((t & k) == 0) ? (!before) : before;
                    if (sw){ sk[t]=kb; sk[p]=ka; si[t]=ib; si[p]=ia; }
                }
                __syncthreads();
            }
        }
        svals[l*NN+t] = sk[t]; sidx[l*NN+t] = si[t];
        int kcnt = (l==0)?K0:(l==1)?K1:K2;
        if (t < kcnt) rev[l*NN + si[t]] = t;
    } else {
        int gid = (blk-3)*512 + t;       // 4096 total
        int i = gid>>3, w = gid&7;
        u64 rm[8];
#pragma unroll
        for (int q = 0; q < 8; q++) rm[q] = ugw[i*8+q];
        u64 acc = 0;
        for (int k = 0; k < NN; k++)
            if ((rm[k>>6] >> (k&63)) & 1ULL) acc |= ugw[k*8+w];
        ug2w[i*8+w] = acc;
    }
}

// ============ A/B precompute ================================================
// A row-major per node (zero-padded k 260..271); B in BF[k>>3][u][k&7] groups.
__device__ __forceinline__ void ab_comp(int jl, const float* __restrict__ We1,
                                        const float* __restrict__ be1, float hval,
                                        int u, int lane,
                                        float* __restrict__ Ap, float* __restrict__ BF){
    const float* W = We1 + jl*130*E2;
    int r  = 4*lane;
    int rt = 256 + lane;
    int rtc = (lane < 4) ? rt : 256;
    F4U av; av.v = *(const float4*)(be1 + jl*E2 + r);
    F4U bv; bv.f[0]=bv.f[1]=bv.f[2]=bv.f[3]=0.0f;
    float avx = be1[jl*E2 + rtc];
    float bvx = 0.0f;
    for (int d = 0; d < DIMF; d++){
        float hv = __shfl(hval, d);
        F4U w1; w1.v = *(const float4*)(W + d*E2 + r);
        F4U w2; w2.v = *(const float4*)(W + (DIMF+d)*E2 + r);
#pragma unroll
        for (int i = 0; i < 4; i++){
            av.f[i] = fmaf(hv, w1.f[i], av.f[i]);
            bv.f[i] = fmaf(hv, w2.f[i], bv.f[i]);
        }
        avx = fmaf(hv, W[d*E2 + rtc], avx);
        bvx = fmaf(hv, W[(DIMF+d)*E2 + rtc], bvx);
    }
    *(float4*)(Ap + u*AS + r) = av.v;
    *(float4*)(BF + ((size_t)(lane>>1)*PADU + u)*8 + (lane&1)*4) = bv.v;
    if (lane < 16){                     // k = 256..271; zero-pad beyond 259
        int k = 256 + lane;
        float aval = (lane < 4) ? avx : 0.0f;
        float bval = (lane < 4) ? bvx : 0.0f;
        Ap[u*AS + k] = aval;
        BF[((size_t)(k>>3)*PADU + u)*8 + (k&7)] = bval;
    }
}

// ============ gather + AB(layer0) + init mi/c0/c1 ===========================
__global__ __launch_bounds__(256) void k_gab(
    const float* __restrict__ feat, const float* __restrict__ coor,
    const float* __restrict__ svals, const int* __restrict__ sidx,
    const float* __restrict__ We1, const float* __restrict__ be1,
    float* __restrict__ hc, float* __restrict__ c0, float* __restrict__ c1,
    float* __restrict__ mi, float* __restrict__ Ap, float* __restrict__ BF){
    int t = threadIdx.x; int u = blockIdx.x*4 + (t>>6); if (u >= KT) return;
    int lane = t&63;
    int l = (u<K0)?0:(u<O2)?1:2;
    int a = u - ((l==0)?0:(l==1)?O1:O2);
    int org = sidx[l*NN+a];
    float val = svals[l*NN+a];
    float hval = feat[org*DIMF+lane]*val;
    hc[u*DIMF+lane] = hval;
    if (lane < 3){ float c = coor[org*3+lane]; c0[u*4+lane]=c; c1[u*4+lane]=c; }
    if (lane == 3){ c0[u*4+3]=0.0f; c1[u*4+3]=0.0f; }
    if (lane < 20) mi[u*20+lane] = 0.0f;
    ab_comp(0, We1, be1, hval, u, lane, Ap, BF);
}

// ============ per-pair edge MLP via MFMA =====================================
// wave = (receiver u, 64-sender tile): two 32-pair MFMA acc sets. Lane owns
// pairs (tile*64+n) and (+32), k-slice c*16+q*8+e. A/wd/we via LDS
// (ds_read_b128, imm offsets), B via 4 dwordx4 off 2 incremented pointers,
// We2 hi/lo frags via 2 dwordx4 off 1 pointer. 3-term bf16-split GEMM.
template<int DOCW>
__global__ __launch_bounds__(256, 4) void k_pair(
    int jl,
    const float* __restrict__ Ap, const float* __restrict__ BF,
    const u16* __restrict__ W2f, const u16* __restrict__ Wc1f,
    const float* __restrict__ wdP, const float* __restrict__ weP,
    const float* __restrict__ be2P, const float* __restrict__ bc1P,
    const float* __restrict__ Wc2P, const float* __restrict__ bc2,
    const float* __restrict__ cin, float* __restrict__ cout,
    float* __restrict__ mi, const int* __restrict__ sidx,
    const u64* __restrict__ ug2w){
    __shared__ __align__(16) char sWK[4*WVLDS];
    __shared__ __align__(16) char sWD[1088];
    __shared__ __align__(16) char sWE[1088];
    int t = threadIdx.x;
    if (t < 68)       ((float4*)sWD)[t]    = *(const float4*)(wdP + jl*KPAD + 4*t);
    else if (t < 136) ((float4*)sWE)[t-68] = *(const float4*)(weP + jl*KPAD + 4*(t-68));
    int wid0 = blockIdx.x*4 + (t>>6);
    int lane = t&63, n = lane&31, q = lane>>5;
    bool dead = (wid0 >= TTOT);
    int wid = dead ? (TTOT-1) : wid0;
    int l, kl, off, a, tile;
    if (wid < T0T)       { l=0; kl=K0; off=0;  a = wid>>3; tile = wid&7; }
    else if (wid < T01T) { int w = wid-T0T;  l=1; kl=K1; off=O1; a = w/NT1; tile = w - a*NT1; }
    else                 { int w = wid-T01T; l=2; kl=K2; off=O2; a = w/NT2; tile = w - a*NT2; }
    int u = off + a;
    int b0 = tile*64 + n, b1 = b0 + 32;
    float act0 = (b0 < kl) ? 1.0f : 0.0f;
    float act1 = (b1 < kl) ? 1.0f : 0.0f;
    int b0c = min(b0, kl-1), b1c = min(b1, kl-1);
    int ub0 = off + b0c, ub1 = off + b1c;
    int ia  = sidx[l*NN+a];
    int ib0 = sidx[l*NN+b0c], ib1 = sidx[l*NN+b1c];
    float ef0 = act0 * (float)((ug2w[ia*8 + (ib0>>6)] >> (ib0&63)) & 1ULL);
    float ef1 = act1 * (float)((ug2w[ia*8 + (ib1>>6)] >> (ib1&63)) & 1ULL);
    F4U ca;  ca.v  = ((const float4*)cin)[u];
    F4U cb0; cb0.v = ((const float4*)cin)[ub0];
    F4U cb1; cb1.v = ((const float4*)cin)[ub1];
    float tx0 = ca.f[0]-cb0.f[0], ty0 = ca.f[1]-cb0.f[1], tz0 = ca.f[2]-cb0.f[2];
    float tx1 = ca.f[0]-cb1.f[0], ty1 = ca.f[1]-cb1.f[1], tz1 = ca.f[2]-cb1.f[2];
    float dd0 = tx0*tx0 + ty0*ty0 + tz0*tz0;
    float dd1 = tx1*tx1 + ty1*ty1 + tz1*tz1;

    char* myk = sWK + (t>>6)*WVLDS;
    {   // stage A for this wave's receiver
        const float* Au = Ap + u*AS;
        ((float4*)myk)[lane] = *(const float4*)(Au + 4*lane);
        if (lane < 4) ((float4*)myk)[64+lane] = *(const float4*)(Au + 256 + 4*lane);
    }
    __syncthreads();

    const float* pB0 = BF + ((size_t)q*PADU + ub0)*8;
    const float* pB1 = BF + ((size_t)q*PADU + ub1)*8;
    const u16*   pW  = W2f + jl*17408 + lane*8;   // FIX R5: was missing +lane*8
    const char*  pA  = myk + q*32;
    const char*  pWD = sWD + q*32;
    const char*  pWE = sWE + q*32;

    f32x16 acc0, acc1;
#pragma unroll
    for (int r = 0; r < 16; r++){ acc0[r] = 0.0f; acc1[r] = 0.0f; }

    for (int c = 0; c < 17; c++){
        F4U b0a, b0b, b1a, b1b, a0, a1, w0, w1, e0, e1;
        b0a.v = *(const float4*)(pB0);     b0b.v = *(const float4*)(pB0 + 4);
        b1a.v = *(const float4*)(pB1);     b1b.v = *(const float4*)(pB1 + 4);
        a0.v = *(const float4*)(pA);       a1.v = *(const float4*)(pA + 16);
        w0.v = *(const float4*)(pWD);      w1.v = *(const float4*)(pWD + 16);
        e0.v = *(const float4*)(pWE);      e1.v = *(const float4*)(pWE + 16);
        SF wh, wl;
        wh.i4 = *(const int4*)(pW);        wl.i4 = *(const int4*)(pW + 512);
        pB0 += 2*PADU*8; pB1 += 2*PADU*8; pW += 1024; pA += 64; pWD += 64; pWE += 64;
        float s0[8], s1[8];
#pragma unroll
        for (int e = 0; e < 4; e++){
            s0[e]   = siluf(fmaf(dd0, w0.f[e], fmaf(ef0, e0.f[e], a0.f[e] + b0a.f[e])));
            s1[e]   = siluf(fmaf(dd1, w0.f[e], fmaf(ef1, e0.f[e], a0.f[e] + b1a.f[e])));
            s0[4+e] = siluf(fmaf(dd0, w1.f[e], fmaf(ef0, e1.f[e], a1.f[e] + b0b.f[e])));
            s1[4+e] = siluf(fmaf(dd1, w1.f[e], fmaf(ef1, e1.f[e], a1.f[e] + b1b.f[e])));
        }
        SF shi0, slo0, shi1, slo1;
#pragma unroll
        for (int p = 0; p < 4; p++){
            float x = s0[2*p], y = s0[2*p+1];
            u32 h = pk_bf16(x, y);
            shi0.w[p] = h;
            slo0.w[p] = pk_bf16(x - __uint_as_float(h << 16),
                                y - __uint_as_float(h & 0xFFFF0000u));
            x = s1[2*p]; y = s1[2*p+1];
            h = pk_bf16(x, y);
            shi1.w[p] = h;
            slo1.w[p] = pk_bf16(x - __uint_as_float(h << 16),
                                y - __uint_as_float(h & 0xFFFF0000u));
        }
        acc0 = __builtin_amdgcn_mfma_f32_32x32x16_bf16(shi0.v, wh.v, acc0, 0, 0, 0);
        acc0 = __builtin_amdgcn_mfma_f32_32x32x16_bf16(slo0.v, wh.v, acc0, 0, 0, 0);
        acc0 = __builtin_amdgcn_mfma_f32_32x32x16_bf16(shi0.v, wl.v, acc0, 0, 0, 0);
        acc1 = __builtin_amdgcn_mfma_f32_32x32x16_bf16(shi1.v, wh.v, acc1, 0, 0, 0);
        acc1 = __builtin_amdgcn_mfma_f32_32x32x16_bf16(slo1.v, wh.v, acc1, 0, 0, 0);
        acc1 = __builtin_amdgcn_mfma_f32_32x32x16_bf16(shi1.v, wl.v, acc1, 0, 0, 0);
    }

    // ---- m = silu(acc + be2); masked m_i sum; (DOCW) repack to LDS bf16
    float be2v = be2P[jl*32 + n];
    u16* mlds = (u16*)myk;               // overwrites A stage (done with it)
    float msum = 0.0f;
#pragma unroll
    for (int r = 0; r < 16; r++){
        int row = (r&3) + 8*(r>>2) + 4*q;
        float m0 = siluf(acc0[r] + be2v);
        float m1 = siluf(acc1[r] + be2v);
        m0 = (tile*64 + row      < kl) ? m0 : 0.0f;
        m1 = (tile*64 + 32 + row < kl) ? m1 : 0.0f;
        msum += m0 + m1;
        if (DOCW){
            mlds[row*MSTR + n]        = bf16_rne(m0);
            mlds[(row+32)*MSTR + n]   = bf16_rne(m1);
        }
    }
    msum += __shfl_xor(msum, 32);
    if (!dead && lane < MD) atomicAdd(&mi[u*20 + lane], msum);

    if (DOCW){
        lgkm_wait();
        const char* mb = (const char*)mlds;
        float gx = 0.0f, gy = 0.0f, gz = 0.0f;
        float bc2v = bc2[jl];
#pragma unroll
        for (int S = 0; S < 2; S++){
            SF af0, af1;
            af0.i4 = *(const int4*)(mb + (S*32+n)*(MSTR*2) + q*16);
            af1.i4 = *(const int4*)(mb + (S*32+n)*(MSTR*2) + 32 + q*16);
            float cwp[16];
#pragma unroll
            for (int r = 0; r < 16; r++) cwp[r] = 0.0f;
            for (int T = 0; T < 3; T++){
                SF bb0, bb1;
                bb0.i4 = *(const int4*)(Wc1f + jl*3072 + T*1024 +       lane*8);
                bb1.i4 = *(const int4*)(Wc1f + jl*3072 + T*1024 + 512 + lane*8);
                f32x16 p2;
#pragma unroll
                for (int r = 0; r < 16; r++) p2[r] = 0.0f;
                p2 = __builtin_amdgcn_mfma_f32_32x32x16_bf16(af0.v, bb0.v, p2, 0, 0, 0);
                p2 = __builtin_amdgcn_mfma_f32_32x32x16_bf16(af1.v, bb1.v, p2, 0, 0, 0);
                float bc1v = bc1P[jl*96 + T*32 + n];
                float wc2v = Wc2P[jl*96 + T*32 + n];
#pragma unroll
                for (int r = 0; r < 16; r++)
                    cwp[r] = fmaf(siluf(p2[r] + bc1v), wc2v, cwp[r]);
            }
#pragma unroll
            for (int r = 0; r < 16; r++){
                int row  = (r&3) + 8*(r>>2) + 4*q + S*32;
                int brow = tile*64 + row;
                F4U cbr; cbr.v = ((const float4*)cin)[off + min(brow, kl-1)];
                float cw = cwp[r] + ((n == 0) ? bc2v : 0.0f);
                cw = (brow < kl) ? cw : 0.0f;
                gx = fmaf(cw, ca.f[0]-cbr.f[0], gx);
                gy = fmaf(cw, ca.f[1]-cbr.f[1], gy);
                gz = fmaf(cw, ca.f[2]-cbr.f[2], gz);
            }
        }
#pragma unroll
        for (int s = 1; s < 64; s <<= 1){
            gx += __shfl_xor(gx, s); gy += __shfl_xor(gy, s); gz += __shfl_xor(gz, s);
        }
        if (!dead && lane == 0){
            atomicAdd(&cout[u*4+0], gx);
            atomicAdd(&cout[u*4+1], gy);
            atomicAdd(&cout[u*4+2], gz);
        }
    }
}

// ============ node MLP + (optionally) AB for next layer + inits ==============
__global__ __launch_bounds__(256) void k_nodeab(
    int jl, int donext, int docopy,
    const float* __restrict__ Wn1, const float* __restrict__ bn1,
    const float* __restrict__ Wn2, const float* __restrict__ bn2,
    const float* __restrict__ We1, const float* __restrict__ be1,
    float* __restrict__ hc, float* __restrict__ mi,
    const float* __restrict__ ccur, float* __restrict__ cnext,
    float* __restrict__ Ap, float* __restrict__ BF){
    int t = threadIdx.x; int u = blockIdx.x*4 + (t>>6); if (u >= KT) return;
    int lane = t&63;
    float hval = hc[u*DIMF+lane];
    float mval = (lane < MD) ? mi[u*20+lane] : 0.0f;
    const float* W1 = Wn1 + jl*(DIMF+MD)*NH1;
    float v0 = bn1[jl*NH1+lane], v1 = bn1[jl*NH1+lane+64];
    for (int d = 0; d < DIMF; d++){
        float x = __shfl(hval, d);
        v0 = fmaf(x, W1[d*NH1+lane],    v0);
        v1 = fmaf(x, W1[d*NH1+lane+64], v1);
    }
    for (int d = 0; d < MD; d++){
        float x = __shfl(mval, d);
        v0 = fmaf(x, W1[(DIMF+d)*NH1+lane],    v0);
        v1 = fmaf(x, W1[(DIMF+d)*NH1+lane+64], v1);
    }
    float s0 = siluf(v0), s1 = siluf(v1);
    const float* W2 = Wn2 + jl*NH1*DIMF;
    float h = bn2[jl*DIMF+lane];
    for (int i = 0; i < 64; i++) h = fmaf(__shfl(s0, i), W2[i*DIMF+lane], h);
    for (int i = 0; i < 64; i++) h = fmaf(__shfl(s1, i), W2[(64+i)*DIMF+lane], h);
    float hn = fmaxf(0.0f, fmaf(2.0f, hval, h));
    hc[u*DIMF+lane] = hn;
    if (donext){
        if (lane < 20) mi[u*20+lane] = 0.0f;
        if (docopy && lane < 4) cnext[u*4+lane] = ccur[u*4+lane];
        ab_comp(jl+1, We1, be1, hn, u, lane, Ap, BF);
    }
}

// ============ scatter + 3-level max =========================================
__global__ void k_final(const float* __restrict__ hc, const int* __restrict__ rev,
                        float* __restrict__ out){
    int gid = blockIdx.x*blockDim.x + threadIdx.x;
    if (gid >= NN*DIMF) return;
    int nn = gid>>6, d = gid&63;
    float v = 0.0f;
    int a0 = rev[0*NN+nn]; if (a0 >= 0) v = fmaxf(v, hc[(0  + a0)*DIMF + d]);
    int a1 = rev[1*NN+nn]; if (a1 >= 0) v = fmaxf(v, hc[(O1 + a1)*DIMF + d]);
    int a2 = rev[2*NN+nn]; if (a2 >= 0) v = fmaxf(v, hc[(O2 + a2)*DIMF + d]);
    out[gid] = v;
}

extern "C" void kernel_launch(void* const* d_in, const int* in_sizes, int n_in,
                              void* d_out, int out_size, void* d_ws, size_t ws_size,
                              hipStream_t stream) {
    (void)in_sizes; (void)n_in; (void)out_size; (void)ws_size;
    const float* feat = (const float*)d_in[0];
    const float* coor = (const float*)d_in[1];
    const float* edge = (const float*)d_in[2];
    const float* We1  = (const float*)d_in[3];
    const float* be1  = (const float*)d_in[4];
    const float* We2  = (const float*)d_in[5];
    const float* be2  = (const float*)d_in[6];
    const float* Wc1  = (const float*)d_in[7];
    const float* bc1  = (const float*)d_in[8];
    const float* Wc2  = (const float*)d_in[9];
    const float* bc2  = (const float*)d_in[10];
    const float* Wn1  = (const float*)d_in[11];
    const float* bn1  = (const float*)d_in[12];
    const float* Wn2  = (const float*)d_in[13];
    const float* bn2  = (const float*)d_in[14];
    const float* wp   = (const float*)d_in[15];
    const float* bp   = (const float*)d_in[16];
    float* out = (float*)d_out;

    char* wsb = (char*)d_ws;
    u64*   ugw    = (u64*)  (wsb + 0);         // 32768
    u64*   ug2w   = (u64*)  (wsb + 32768);     // 32768
    float* scores = (float*)(wsb + 65536);     // 6144
    float* svals  = (float*)(wsb + 71680);     // 6144
    int*   sidx   = (int*)  (wsb + 77824);     // 6144
    int*   rev    = (int*)  (wsb + 83968);     // 6144
    float* c0     = (float*)(wsb + 90112);     // 18432
    float* c1     = (float*)(wsb + 108544);    // 18432
    float* mi     = (float*)(wsb + 126976);    // 90112
    float* hc     = (float*)(wsb + 217088);    // 288256
    float* Ap     = (float*)(wsb + 505344);    // 1224192
    float* BF     = (float*)(wsb + 1729536);   // 1253376 (34*1152*8*4)
    u16*   W2f    = (u16*)  (wsb + 2982912);   // 104448  (3*17*2*512*2)
    u16*   Wc1f   = (u16*)  (wsb + 3087360);   // 18432
    float* wdP    = (float*)(wsb + 3105792);   // 3328
    float* weP    = (float*)(wsb + 3109120);   // 3328
    float* be2P   = (float*)(wsb + 3112448);   // 384
    float* bc1P   = (float*)(wsb + 3112832);   // 1152
    float* Wc2P   = (float*)(wsb + 3113984);   // 1152  (end ~3.12 MB)

    k_pre<<<383, 256, 0, stream>>>(edge, feat, wp, bp, We2, Wc1, We1, be2, bc1, Wc2,
                                   ugw, scores, W2f, Wc1f,
                                   wdP, weP, be2P, bc1P, Wc2P);
    k_sortug2<<<11, 512, 0, stream>>>(scores, ugw, svals, sidx, rev, ug2w);
    k_gab<<<282, 256, 0, stream>>>(feat, coor, svals, sidx, We1, be1,
                                   hc, c0, c1, mi, Ap, BF);
    // layer 0: cin=c0, cout=c1
    k_pair<1><<<PBLK, 256, 0, stream>>>(0, Ap, BF, W2f, Wc1f,
                                        wdP, weP, be2P, bc1P, Wc2P, bc2,
                                        c0, c1, mi, sidx, ug2w);
    k_nodeab<<<282, 256, 0, stream>>>(0, 1, 1, Wn1, bn1, Wn2, bn2, We1, be1,
                                      hc, mi, c1, c0, Ap, BF);
    // layer 1: cin=c1, cout=c0 (pre-initialized to c1 by k_nodeab)
    k_pair<1><<<PBLK, 256, 0, stream>>>(1, Ap, BF, W2f, Wc1f,
                                        wdP, weP, be2P, bc1P, Wc2P, bc2,
                                        c1, c0, mi, sidx, ug2w);
    k_nodeab<<<282, 256, 0, stream>>>(1, 1, 0, Wn1, bn1, Wn2, bn2, We1, be1,
                                      hc, mi, c0, c1, Ap, BF);
    // layer 2: coords output unused -> no coord MLP instantiation
    k_pair<0><<<PBLK, 256, 0, stream>>>(2, Ap, BF, W2f, Wc1f,
                                        wdP, weP, be2P, bc1P, Wc2P, bc2,
                                        c0, c1, mi, sidx, ug2w);
    k_nodeab<<<282, 256, 0, stream>>>(2, 0, 0, Wn1, bn1, Wn2, bn2, We1, be1,
                                      hc, mi, c0, c1, Ap, BF);
    k_final<<<128, 256, 0, stream>>>(hc, rev, out);
}

// Round 7
// 417.835 us; speedup vs baseline: 2.1173x; 1.0731x over previous
//
#include <hip/hip_runtime.h>
#include <hip/hip_bf16.h>

typedef unsigned long long u64;
typedef unsigned int u32;
typedef unsigned short u16;

#define NN   512
#define DIMF 64
#define E2   260
#define KPAD 272
#define MD   17
#define MH   68
#define NH1  128
#define K0   460
#define K1   358
#define K2   307
#define KT   1125
#define O1   460
#define O2   818
#define PADU 1152
#define AS   272
// 64-sender tiles per receiver, one wave each (2 MFMA acc sets of 32)
#define NT0  8
#define NT1  6
#define NT2  5
#define T0T   (K0*NT0)          // 3680
#define T01T  (T0T + K1*NT1)    // 5828
#define TTOT  (T01T + K2*NT2)   // 7363
#define PBLK  ((TTOT+3)/4)      // 1841
#define MSTR  32                // u16 stride of m-repack rows (64 B, 16B-aligned; 2-way bank alias = free)
#define WVLDS 4096              // per-wave LDS scratch bytes (A-stage 1088B, m-repack 4096B)

typedef __attribute__((ext_vector_type(8)))  short short8;
typedef __attribute__((ext_vector_type(16))) float f32x16;

union SF  { int4 i4; u16 us[8]; u32 w[4]; short8 v; };
union F4U { float4 v; float f[4]; };

__device__ __forceinline__ float fast_exp2(float x){
#if __has_builtin(__builtin_amdgcn_exp2f)
    return __builtin_amdgcn_exp2f(x);
#else
    return __expf(x * 0.6931471805599453f);
#endif
}
__device__ __forceinline__ float fast_rcp(float x){
#if __has_builtin(__builtin_amdgcn_rcpf)
    return __builtin_amdgcn_rcpf(x);
#else
    return __fdividef(1.0f, x);
#endif
}
__device__ __forceinline__ float siluf(float x){
    return x * fast_rcp(1.0f + fast_exp2(x * -1.4426950408889634f));
}
__device__ __forceinline__ float sigf(float x){
    return fast_rcp(1.0f + fast_exp2(x * -1.4426950408889634f));
}
__device__ __forceinline__ u16 bf16_rne(float f){
    u32 u = __float_as_uint(f);
    u += 0x7FFFu + ((u >> 16) & 1u);
    return (u16)(u >> 16);
}
__device__ __forceinline__ float bf16f(u16 h){
    return __uint_as_float(((u32)h) << 16);
}
__device__ __forceinline__ u32 pk_bf16(float x, float y){
    float2 f2; f2.x = x; f2.y = y;
    __hip_bfloat162 h = __float22bfloat162_rn(f2);
    union { __hip_bfloat162 b; u32 u; } cv; cv.b = h;
    return cv.u;
}
__device__ __forceinline__ void lgkm_wait(){
#if __has_builtin(__builtin_amdgcn_s_waitcnt)
    __builtin_amdgcn_s_waitcnt(0xC07F);   // lgkmcnt(0)
#endif
}

// ============ fused prep: ug bitmasks + pooling scores + weight fragments ===
__global__ __launch_bounds__(256) void k_pre(
    const float* __restrict__ edge, const float* __restrict__ feat,
    const float* __restrict__ wp, const float* __restrict__ bp,
    const float* __restrict__ We2, const float* __restrict__ Wc1,
    const float* __restrict__ We1, const float* __restrict__ be2,
    const float* __restrict__ bc1, const float* __restrict__ Wc2,
    u64* __restrict__ ugw, float* __restrict__ scores,
    u16* __restrict__ W2f, u16* __restrict__ Wc1f,
    float* __restrict__ wdP, float* __restrict__ weP, float* __restrict__ be2P,
    float* __restrict__ bc1P, float* __restrict__ Wc2P, u64* __restrict__ ug2w){
    int blk = blockIdx.x, t = threadIdx.x;
    if (blk < 128){                      // ug row bitmasks, 4 rows/block
        int i = blk*4 + (t>>6); int lane = t&63;
        const float* row = edge + (size_t)i*NN;
        for (int w = 0; w < 8; w++){
            u64 m = __ballot(row[w*64+lane] != 0.0f);
            if (lane == 0) ugw[i*8+w] = m;
        }
        return;
    }
    if (blk < 134){                      // pooling scores
        int gid = (blk-128)*256 + t; if (gid >= 3*NN) return;
        int l = gid>>9, n = gid&511;
        float s = bp[l];
        for (int d = 0; d < DIMF; d++) s = fmaf(feat[n*DIMF+d], wp[l*DIMF+d], s);
        scores[gid] = sigf(s);
        return;
    }
    int idx = (blk-134)*256 + t;
    if (idx < 52224){                    // We2 frags interleaved hi/lo: [jl][c17][hl2][lane][8]
        int e = idx&7, lane = (idx>>3)&63, hl = (idx>>9)&1, c = (idx>>10)%17, jl = idx/17408;
        int q = lane>>5, nn = lane&31;
        int k = c*16 + q*8 + e;
        float v = (k < E2 && nn < MD) ? We2[jl*E2*MD + k*MD + nn] : 0.0f;
        u16 hi = bf16_rne(v);
        W2f[idx] = hl ? bf16_rne(v - bf16f(hi)) : hi;
        return;
    }
    idx -= 52224;
    if (idx < 9216){                     // Wc1 frags: [jl][T3][c2][lane][8]
        int e = idx & 7, lane = (idx>>3)&63, c2 = (idx>>9)&1, T = (idx>>10)%3, jl = idx/3072;
        int q = lane>>5, nn = lane&31;
        int o = c2*16 + q*8 + e, h = T*32 + nn;
        float v = (o < MD && h < MH) ? Wc1[jl*MD*MH + o*MH + h] : 0.0f;
        Wc1f[idx] = bf16_rne(v);
        return;
    }
    idx -= 9216;
    if (idx < 816){ int jl = idx/KPAD, k = idx%KPAD;
        wdP[idx] = (k < E2) ? We1[jl*130*E2 + 128*E2 + k] : 0.0f; return; }
    idx -= 816;
    if (idx < 816){ int jl = idx/KPAD, k = idx%KPAD;
        weP[idx] = (k < E2) ? We1[jl*130*E2 + 129*E2 + k] : 0.0f; return; }
    idx -= 816;
    if (idx < 96){ int jl = idx/32, o = idx%32;
        be2P[idx] = (o < MD) ? be2[jl*MD+o] : 0.0f; return; }
    idx -= 96;
    if (idx < 288){ int jl = idx/96, h = idx%96;
        bc1P[idx] = (h < MH) ? bc1[jl*MH+h] : 0.0f; return; }
    idx -= 288;
    if (idx < 288){ int jl = idx/96, h = idx%96;
        Wc2P[idx] = (h < MH) ? Wc2[jl*MH+h] : 0.0f; return; }
    idx -= 288;
    if (idx < 4096){ ug2w[idx] = 0ULL; return; }   // zero for k_sortug2's atomicOr
}

// ============ fused: bitonic sort (3 blocks) + ug2 bitset matmul (64 blocks) =
__global__ __launch_bounds__(512) void k_sortug2(
    const float* __restrict__ scores, const u64* __restrict__ ugw,
    float* __restrict__ svals, int* __restrict__ sidx, int* __restrict__ rev,
    u64* __restrict__ ug2w){
    int blk = blockIdx.x, t = threadIdx.x;
    if (blk < 3){
        int l = blk;
        __shared__ float sk[NN];
        __shared__ int   si[NN];
        sk[t] = scores[l*NN+t]; si[t] = t; rev[l*NN+t] = -1;
        __syncthreads();
        for (int k = 2; k <= NN; k <<= 1){
            for (int jj = k>>1; jj > 0; jj >>= 1){
                int p = t ^ jj;
                if (p > t){
                    float ka = sk[t], kb = sk[p];
                    int ia = si[t], ib = si[p];
                    bool before = (ka > kb) || (ka == kb && ia < ib);
                    bool sw = ((t & k) == 0) ? (!before) : before;
                    if (sw){ sk[t]=kb; sk[p]=ka; si[t]=ib; si[p]=ia; }
                }
                __syncthreads();
            }
        }
        svals[l*NN+t] = sk[t]; sidx[l*NN+t] = si[t];
        int kcnt = (l==0)?K0:(l==1)?K1:K2;
        if (t < kcnt) rev[l*NN + si[t]] = t;
    } else {
        // (i, w, kc): row i, out-word w, row-mask word kc. Iterate SET BITS only
        // (~3.2 bits/word at 5% edge density) and atomicOr the partial.
        int gid = (blk-3)*512 + t;       // 32768 total
        int i  = gid >> 6;
        int w  = (gid >> 3) & 7;
        int kc = gid & 7;
        u64 rm = ugw[i*8 + kc];
        u64 acc = 0;
        int base = kc*64;
        while (rm){
            int k2 = __builtin_ctzll(rm);
            rm &= rm - 1;
            acc |= ugw[(base + k2)*8 + w];
        }
        if (acc) atomicOr(&ug2w[i*8 + w], acc);
    }
}

// ============ A/B precompute ================================================
// A row-major per node (zero-padded k 260..271); B in BF[k>>3][u][k&7] groups.
__device__ __forceinline__ void ab_comp(int jl, const float* __restrict__ We1,
                                        const float* __restrict__ be1, float hval,
                                        int u, int lane,
                                        float* __restrict__ Ap, float* __restrict__ BF){
    const float* W = We1 + jl*130*E2;
    int r  = 4*lane;
    int rt = 256 + lane;
    int rtc = (lane < 4) ? rt : 256;
    F4U av; av.v = *(const float4*)(be1 + jl*E2 + r);
    F4U bv; bv.f[0]=bv.f[1]=bv.f[2]=bv.f[3]=0.0f;
    float avx = be1[jl*E2 + rtc];
    float bvx = 0.0f;
    for (int d = 0; d < DIMF; d++){
        float hv = __shfl(hval, d);
        F4U w1; w1.v = *(const float4*)(W + d*E2 + r);
        F4U w2; w2.v = *(const float4*)(W + (DIMF+d)*E2 + r);
#pragma unroll
        for (int i = 0; i < 4; i++){
            av.f[i] = fmaf(hv, w1.f[i], av.f[i]);
            bv.f[i] = fmaf(hv, w2.f[i], bv.f[i]);
        }
        avx = fmaf(hv, W[d*E2 + rtc], avx);
        bvx = fmaf(hv, W[(DIMF+d)*E2 + rtc], bvx);
    }
    *(float4*)(Ap + u*AS + r) = av.v;
    *(float4*)(BF + ((size_t)(lane>>1)*PADU + u)*8 + (lane&1)*4) = bv.v;
    if (lane < 16){                     // k = 256..271; zero-pad beyond 259
        int k = 256 + lane;
        float aval = (lane < 4) ? avx : 0.0f;
        float bval = (lane < 4) ? bvx : 0.0f;
        Ap[u*AS + k] = aval;
        BF[((size_t)(k>>3)*PADU + u)*8 + (k&7)] = bval;
    }
}

// ============ gather + AB(layer0) + init mi/c0/c1 ===========================
__global__ __launch_bounds__(256) void k_gab(
    const float* __restrict__ feat, const float* __restrict__ coor,
    const float* __restrict__ svals, const int* __restrict__ sidx,
    const float* __restrict__ We1, const float* __restrict__ be1,
    float* __restrict__ hc, float* __restrict__ c0, float* __restrict__ c1,
    float* __restrict__ mi, float* __restrict__ Ap, float* __restrict__ BF){
    int t = threadIdx.x; int u = blockIdx.x*4 + (t>>6); if (u >= KT) return;
    int lane = t&63;
    int l = (u<K0)?0:(u<O2)?1:2;
    int a = u - ((l==0)?0:(l==1)?O1:O2);
    int org = sidx[l*NN+a];
    float val = svals[l*NN+a];
    float hval = feat[org*DIMF+lane]*val;
    hc[u*DIMF+lane] = hval;
    if (lane < 3){ float c = coor[org*3+lane]; c0[u*4+lane]=c; c1[u*4+lane]=c; }
    if (lane == 3){ c0[u*4+3]=0.0f; c1[u*4+3]=0.0f; }
    if (lane < 20) mi[u*20+lane] = 0.0f;
    ab_comp(0, We1, be1, hval, u, lane, Ap, BF);
}

// ============ per-pair edge MLP via MFMA =====================================
// wave = (receiver u, 64-sender tile): two 32-pair MFMA acc sets. Lane owns
// pairs (tile*64+n) and (+32), k-slice c*16+q*8+e. Software-pipelined: c+1's
// 6 global loads (B x4, We2-frag x2) issued before computing c. A/wd/we via
// LDS ds_read_b128. 3-term bf16-split GEMM into 32x32x16 MFMA.
template<int DOCW>
__global__ __launch_bounds__(256, 3) void k_pair(
    int jl,
    const float* __restrict__ Ap, const float* __restrict__ BF,
    const u16* __restrict__ W2f, const u16* __restrict__ Wc1f,
    const float* __restrict__ wdP, const float* __restrict__ weP,
    const float* __restrict__ be2P, const float* __restrict__ bc1P,
    const float* __restrict__ Wc2P, const float* __restrict__ bc2,
    const float* __restrict__ cin, float* __restrict__ cout,
    float* __restrict__ mi, const int* __restrict__ sidx,
    const u64* __restrict__ ug2w){
    __shared__ __align__(16) char sWK[4*WVLDS];
    __shared__ __align__(16) char sWD[1088];
    __shared__ __align__(16) char sWE[1088];
    int t = threadIdx.x;
    if (t < 68)       ((float4*)sWD)[t]    = *(const float4*)(wdP + jl*KPAD + 4*t);
    else if (t < 136) ((float4*)sWE)[t-68] = *(const float4*)(weP + jl*KPAD + 4*(t-68));
    int wid0 = blockIdx.x*4 + (t>>6);
    int lane = t&63, n = lane&31, q = lane>>5;
    bool dead = (wid0 >= TTOT);
    int wid = dead ? (TTOT-1) : wid0;
    int l, kl, off, a, tile;
    if (wid < T0T)       { l=0; kl=K0; off=0;  a = wid>>3; tile = wid&7; }
    else if (wid < T01T) { int w = wid-T0T;  l=1; kl=K1; off=O1; a = w/NT1; tile = w - a*NT1; }
    else                 { int w = wid-T01T; l=2; kl=K2; off=O2; a = w/NT2; tile = w - a*NT2; }
    int u = off + a;
    int b0 = tile*64 + n, b1 = b0 + 32;
    float act0 = (b0 < kl) ? 1.0f : 0.0f;
    float act1 = (b1 < kl) ? 1.0f : 0.0f;
    int b0c = min(b0, kl-1), b1c = min(b1, kl-1);
    int ub0 = off + b0c, ub1 = off + b1c;
    int ia  = sidx[l*NN+a];
    int ib0 = sidx[l*NN+b0c], ib1 = sidx[l*NN+b1c];
    float ef0 = act0 * (float)((ug2w[ia*8 + (ib0>>6)] >> (ib0&63)) & 1ULL);
    float ef1 = act1 * (float)((ug2w[ia*8 + (ib1>>6)] >> (ib1&63)) & 1ULL);
    F4U ca;  ca.v  = ((const float4*)cin)[u];
    F4U cb0; cb0.v = ((const float4*)cin)[ub0];
    F4U cb1; cb1.v = ((const float4*)cin)[ub1];
    float tx0 = ca.f[0]-cb0.f[0], ty0 = ca.f[1]-cb0.f[1], tz0 = ca.f[2]-cb0.f[2];
    float tx1 = ca.f[0]-cb1.f[0], ty1 = ca.f[1]-cb1.f[1], tz1 = ca.f[2]-cb1.f[2];
    float dd0 = tx0*tx0 + ty0*ty0 + tz0*tz0;
    float dd1 = tx1*tx1 + ty1*ty1 + tz1*tz1;

    char* myk = sWK + (t>>6)*WVLDS;
    {   // stage A for this wave's receiver
        const float* Au = Ap + u*AS;
        ((float4*)myk)[lane] = *(const float4*)(Au + 4*lane);
        if (lane < 4) ((float4*)myk)[64+lane] = *(const float4*)(Au + 256 + 4*lane);
    }
    __syncthreads();

    const float* pB0 = BF + ((size_t)q*PADU + ub0)*8;
    const float* pB1 = BF + ((size_t)q*PADU + ub1)*8;
    const u16*   pW  = W2f + jl*17408 + lane*8;
    const char*  pA  = myk + q*32;
    const char*  pWD = sWD + q*32;
    const char*  pWE = sWE + q*32;

    f32x16 acc0, acc1;
#pragma unroll
    for (int r = 0; r < 16; r++){ acc0[r] = 0.0f; acc1[r] = 0.0f; }

    // prologue loads for c=0
    F4U nb0a, nb0b, nb1a, nb1b; SF nwh, nwl;
    nb0a.v = *(const float4*)(pB0);     nb0b.v = *(const float4*)(pB0 + 4);
    nb1a.v = *(const float4*)(pB1);     nb1b.v = *(const float4*)(pB1 + 4);
    nwh.i4 = *(const int4*)(pW);        nwl.i4 = *(const int4*)(pW + 512);

    for (int c = 0; c < 17; c++){
        F4U b0a = nb0a, b0b = nb0b, b1a = nb1a, b1b = nb1b;
        SF  wh  = nwh,  wl  = nwl;
        pB0 += 2*PADU*8; pB1 += 2*PADU*8; pW += 1024;
        if (c < 16){   // issue c+1's global loads before computing c
            nb0a.v = *(const float4*)(pB0);     nb0b.v = *(const float4*)(pB0 + 4);
            nb1a.v = *(const float4*)(pB1);     nb1b.v = *(const float4*)(pB1 + 4);
            nwh.i4 = *(const int4*)(pW);        nwl.i4 = *(const int4*)(pW + 512);
        }
        F4U a0, a1, w0, w1, e0, e1;
        a0.v = *(const float4*)(pA);       a1.v = *(const float4*)(pA + 16);
        w0.v = *(const float4*)(pWD);      w1.v = *(const float4*)(pWD + 16);
        e0.v = *(const float4*)(pWE);      e1.v = *(const float4*)(pWE + 16);
        pA += 64; pWD += 64; pWE += 64;
        float s0[8], s1[8];
#pragma unroll
        for (int e = 0; e < 4; e++){
            s0[e]   = siluf(fmaf(dd0, w0.f[e], fmaf(ef0, e0.f[e], a0.f[e] + b0a.f[e])));
            s1[e]   = siluf(fmaf(dd1, w0.f[e], fmaf(ef1, e0.f[e], a0.f[e] + b1a.f[e])));
            s0[4+e] = siluf(fmaf(dd0, w1.f[e], fmaf(ef0, e1.f[e], a1.f[e] + b0b.f[e])));
            s1[4+e] = siluf(fmaf(dd1, w1.f[e], fmaf(ef1, e1.f[e], a1.f[e] + b1b.f[e])));
        }
        SF shi0, slo0, shi1, slo1;
#pragma unroll
        for (int p = 0; p < 4; p++){
            float x = s0[2*p], y = s0[2*p+1];
            u32 h = pk_bf16(x, y);
            shi0.w[p] = h;
            slo0.w[p] = pk_bf16(x - __uint_as_float(h << 16),
                                y - __uint_as_float(h & 0xFFFF0000u));
            x = s1[2*p]; y = s1[2*p+1];
            h = pk_bf16(x, y);
            shi1.w[p] = h;
            slo1.w[p] = pk_bf16(x - __uint_as_float(h << 16),
                                y - __uint_as_float(h & 0xFFFF0000u));
        }
        acc0 = __builtin_amdgcn_mfma_f32_32x32x16_bf16(shi0.v, wh.v, acc0, 0, 0, 0);
        acc0 = __builtin_amdgcn_mfma_f32_32x32x16_bf16(slo0.v, wh.v, acc0, 0, 0, 0);
        acc0 = __builtin_amdgcn_mfma_f32_32x32x16_bf16(shi0.v, wl.v, acc0, 0, 0, 0);
        acc1 = __builtin_amdgcn_mfma_f32_32x32x16_bf16(shi1.v, wh.v, acc1, 0, 0, 0);
        acc1 = __builtin_amdgcn_mfma_f32_32x32x16_bf16(slo1.v, wh.v, acc1, 0, 0, 0);
        acc1 = __builtin_amdgcn_mfma_f32_32x32x16_bf16(shi1.v, wl.v, acc1, 0, 0, 0);
    }

    // ---- m = silu(acc + be2); masked m_i sum; (DOCW) repack to LDS bf16
    float be2v = be2P[jl*32 + n];
    u16* mlds = (u16*)myk;               // overwrites A stage (done with it)
    float msum = 0.0f;
#pragma unroll
    for (int r = 0; r < 16; r++){
        int row = (r&3) + 8*(r>>2) + 4*q;
        float m0 = siluf(acc0[r] + be2v);
        float m1 = siluf(acc1[r] + be2v);
        m0 = (tile*64 + row      < kl) ? m0 : 0.0f;
        m1 = (tile*64 + 32 + row < kl) ? m1 : 0.0f;
        msum += m0 + m1;
        if (DOCW){
            mlds[row*MSTR + n]        = bf16_rne(m0);
            mlds[(row+32)*MSTR + n]   = bf16_rne(m1);
        }
    }
    msum += __shfl_xor(msum, 32);
    if (!dead && lane < MD) atomicAdd(&mi[u*20 + lane], msum);

    if (DOCW){
        lgkm_wait();
        const char* mb = (const char*)mlds;
        float gx = 0.0f, gy = 0.0f, gz = 0.0f;
        float bc2v = bc2[jl];
#pragma unroll
        for (int S = 0; S < 2; S++){
            SF af0, af1;
            af0.i4 = *(const int4*)(mb + (S*32+n)*(MSTR*2) + q*16);
            af1.i4 = *(const int4*)(mb + (S*32+n)*(MSTR*2) + 32 + q*16);
            float cwp[16];
#pragma unroll
            for (int r = 0; r < 16; r++) cwp[r] = 0.0f;
            for (int T = 0; T < 3; T++){
                SF bb0, bb1;
                bb0.i4 = *(const int4*)(Wc1f + jl*3072 + T*1024 +       lane*8);
                bb1.i4 = *(const int4*)(Wc1f + jl*3072 + T*1024 + 512 + lane*8);
                f32x16 p2;
#pragma unroll
                for (int r = 0; r < 16; r++) p2[r] = 0.0f;
                p2 = __builtin_amdgcn_mfma_f32_32x32x16_bf16(af0.v, bb0.v, p2, 0, 0, 0);
                p2 = __builtin_amdgcn_mfma_f32_32x32x16_bf16(af1.v, bb1.v, p2, 0, 0, 0);
                float bc1v = bc1P[jl*96 + T*32 + n];
                float wc2v = Wc2P[jl*96 + T*32 + n];
#pragma unroll
                for (int r = 0; r < 16; r++)
                    cwp[r] = fmaf(siluf(p2[r] + bc1v), wc2v, cwp[r]);
            }
#pragma unroll
            for (int r = 0; r < 16; r++){
                int row  = (r&3) + 8*(r>>2) + 4*q + S*32;
                int brow = tile*64 + row;
                F4U cbr; cbr.v = ((const float4*)cin)[off + min(brow, kl-1)];
                float cw = cwp[r] + ((n == 0) ? bc2v : 0.0f);
                cw = (brow < kl) ? cw : 0.0f;
                gx = fmaf(cw, ca.f[0]-cbr.f[0], gx);
                gy = fmaf(cw, ca.f[1]-cbr.f[1], gy);
                gz = fmaf(cw, ca.f[2]-cbr.f[2], gz);
            }
        }
#pragma unroll
        for (int s = 1; s < 64; s <<= 1){
            gx += __shfl_xor(gx, s); gy += __shfl_xor(gy, s); gz += __shfl_xor(gz, s);
        }
        if (!dead && lane == 0){
            atomicAdd(&cout[u*4+0], gx);
            atomicAdd(&cout[u*4+1], gy);
            atomicAdd(&cout[u*4+2], gz);
        }
    }
}

// ============ node MLP + (optionally) AB for next layer + inits ==============
__global__ __launch_bounds__(256) void k_nodeab(
    int jl, int donext, int docopy,
    const float* __restrict__ Wn1, const float* __restrict__ bn1,
    const float* __restrict__ Wn2, const float* __restrict__ bn2,
    const float* __restrict__ We1, const float* __restrict__ be1,
    float* __restrict__ hc, float* __restrict__ mi,
    const float* __restrict__ ccur, float* __restrict__ cnext,
    float* __restrict__ Ap, float* __restrict__ BF){
    int t = threadIdx.x; int u = blockIdx.x*4 + (t>>6); if (u >= KT) return;
    int lane = t&63;
    float hval = hc[u*DIMF+lane];
    float mval = (lane < MD) ? mi[u*20+lane] : 0.0f;
    const float* W1 = Wn1 + jl*(DIMF+MD)*NH1;
    float v0 = bn1[jl*NH1+lane], v1 = bn1[jl*NH1+lane+64];
    for (int d = 0; d < DIMF; d++){
        float x = __shfl(hval, d);
        v0 = fmaf(x, W1[d*NH1+lane],    v0);
        v1 = fmaf(x, W1[d*NH1+lane+64], v1);
    }
    for (int d = 0; d < MD; d++){
        float x = __shfl(mval, d);
        v0 = fmaf(x, W1[(DIMF+d)*NH1+lane],    v0);
        v1 = fmaf(x, W1[(DIMF+d)*NH1+lane+64], v1);
    }
    float s0 = siluf(v0), s1 = siluf(v1);
    const float* W2 = Wn2 + jl*NH1*DIMF;
    float h = bn2[jl*DIMF+lane];
    for (int i = 0; i < 64; i++) h = fmaf(__shfl(s0, i), W2[i*DIMF+lane], h);
    for (int i = 0; i < 64; i++) h = fmaf(__shfl(s1, i), W2[(64+i)*DIMF+lane], h);
    float hn = fmaxf(0.0f, fmaf(2.0f, hval, h));
    hc[u*DIMF+lane] = hn;
    if (donext){
        if (lane < 20) mi[u*20+lane] = 0.0f;
        if (docopy && lane < 4) cnext[u*4+lane] = ccur[u*4+lane];
        ab_comp(jl+1, We1, be1, hn, u, lane, Ap, BF);
    }
}

// ============ scatter + 3-level max =========================================
__global__ void k_final(const float* __restrict__ hc, const int* __restrict__ rev,
                        float* __restrict__ out){
    int gid = blockIdx.x*blockDim.x + threadIdx.x;
    if (gid >= NN*DIMF) return;
    int nn = gid>>6, d = gid&63;
    float v = 0.0f;
    int a0 = rev[0*NN+nn]; if (a0 >= 0) v = fmaxf(v, hc[(0  + a0)*DIMF + d]);
    int a1 = rev[1*NN+nn]; if (a1 >= 0) v = fmaxf(v, hc[(O1 + a1)*DIMF + d]);
    int a2 = rev[2*NN+nn]; if (a2 >= 0) v = fmaxf(v, hc[(O2 + a2)*DIMF + d]);
    out[gid] = v;
}

extern "C" void kernel_launch(void* const* d_in, const int* in_sizes, int n_in,
                              void* d_out, int out_size, void* d_ws, size_t ws_size,
                              hipStream_t stream) {
    (void)in_sizes; (void)n_in; (void)out_size; (void)ws_size;
    const float* feat = (const float*)d_in[0];
    const float* coor = (const float*)d_in[1];
    const float* edge = (const float*)d_in[2];
    const float* We1  = (const float*)d_in[3];
    const float* be1  = (const float*)d_in[4];
    const float* We2  = (const float*)d_in[5];
    const float* be2  = (const float*)d_in[6];
    const float* Wc1  = (const float*)d_in[7];
    const float* bc1  = (const float*)d_in[8];
    const float* Wc2  = (const float*)d_in[9];
    const float* bc2  = (const float*)d_in[10];
    const float* Wn1  = (const float*)d_in[11];
    const float* bn1  = (const float*)d_in[12];
    const float* Wn2  = (const float*)d_in[13];
    const float* bn2  = (const float*)d_in[14];
    const float* wp   = (const float*)d_in[15];
    const float* bp   = (const float*)d_in[16];
    float* out = (float*)d_out;

    char* wsb = (char*)d_ws;
    u64*   ugw    = (u64*)  (wsb + 0);         // 32768
    u64*   ug2w   = (u64*)  (wsb + 32768);     // 32768
    float* scores = (float*)(wsb + 65536);     // 6144
    float* svals  = (float*)(wsb + 71680);     // 6144
    int*   sidx   = (int*)  (wsb + 77824);     // 6144
    int*   rev    = (int*)  (wsb + 83968);     // 6144
    float* c0     = (float*)(wsb + 90112);     // 18432
    float* c1     = (float*)(wsb + 108544);    // 18432
    float* mi     = (float*)(wsb + 126976);    // 90112
    float* hc     = (float*)(wsb + 217088);    // 288256
    float* Ap     = (float*)(wsb + 505344);    // 1224192
    float* BF     = (float*)(wsb + 1729536);   // 1253376 (34*1152*8*4)
    u16*   W2f    = (u16*)  (wsb + 2982912);   // 104448  (3*17*2*512*2)
    u16*   Wc1f   = (u16*)  (wsb + 3087360);   // 18432
    float* wdP    = (float*)(wsb + 3105792);   // 3328
    float* weP    = (float*)(wsb + 3109120);   // 3328
    float* be2P   = (float*)(wsb + 3112448);   // 384
    float* bc1P   = (float*)(wsb + 3112832);   // 1152
    float* Wc2P   = (float*)(wsb + 3113984);   // 1152  (end ~3.12 MB)

    k_pre<<<399, 256, 0, stream>>>(edge, feat, wp, bp, We2, Wc1, We1, be2, bc1, Wc2,
                                   ugw, scores, W2f, Wc1f,
                                   wdP, weP, be2P, bc1P, Wc2P, ug2w);
    k_sortug2<<<67, 512, 0, stream>>>(scores, ugw, svals, sidx, rev, ug2w);
    k_gab<<<282, 256, 0, stream>>>(feat, coor, svals, sidx, We1, be1,
                                   hc, c0, c1, mi, Ap, BF);
    // layer 0: cin=c0, cout=c1
    k_pair<1><<<PBLK, 256, 0, stream>>>(0, Ap, BF, W2f, Wc1f,
                                        wdP, weP, be2P, bc1P, Wc2P, bc2,
                                        c0, c1, mi, sidx, ug2w);
    k_nodeab<<<282, 256, 0, stream>>>(0, 1, 1, Wn1, bn1, Wn2, bn2, We1, be1,
                                      hc, mi, c1, c0, Ap, BF);
    // layer 1: cin=c1, cout=c0 (pre-initialized to c1 by k_nodeab)
    k_pair<1><<<PBLK, 256, 0, stream>>>(1, Ap, BF, W2f, Wc1f,
                                        wdP, weP, be2P, bc1P, Wc2P, bc2,
                                        c1, c0, mi, sidx, ug2w);
    k_nodeab<<<282, 256, 0, stream>>>(1, 1, 0, Wn1, bn1, Wn2, bn2, We1, be1,
                                      hc, mi, c0, c1, Ap, BF);
    // layer 2: coords output unused -> no coord MLP instantiation
    k_pair<0><<<PBLK, 256, 0, stream>>>(2, Ap, BF, W2f, Wc1f,
                                        wdP, weP, be2P, bc1P, Wc2P, bc2,
                                        c0, c1, mi, sidx, ug2w);
    k_nodeab<<<282, 256, 0, stream>>>(2, 0, 0, Wn1, bn1, Wn2, bn2, We1, be1,
                                      hc, mi, c0, c1, Ap, BF);
    k_final<<<128, 256, 0, stream>>>(hc, rev, out);
}